// Round 7
// baseline (462.264 us; speedup 1.0000x reference)
//
#include <hip/hip_runtime.h>
#include <math.h>

#define M_TOK 4096           // B*S
#define HID   2048
#define NEXP  8
#define CAP   1536
#define DISP_ELEMS 50331648ull   // 4096*8*1536
#define NTOT  5120               // 1024 + 2048 + 2048 (concat N)
#define ZTOT4 25165824ull        // (2*DISP_ELEMS)/4 float4s
#define NCOMP 320                // compute blocks (16 M x 20 N)
#define NZERO 192                // co-dispatched zerofill blocks

typedef __attribute__((ext_vector_type(8))) short bf16x8;
typedef __attribute__((ext_vector_type(4))) float f32x4;

__device__ __forceinline__ unsigned short f2bf(float f) {
  unsigned u = __float_as_uint(f);
  unsigned r = u + 0x7FFFu + ((u >> 16) & 1u);   // RNE (finite inputs)
  return (unsigned short)(r >> 16);
}
__device__ __forceinline__ float bf2f(unsigned short h) {
  return __uint_as_float(((unsigned)h) << 16);
}

__device__ __forceinline__ void gload16(const void* g, void* l) {
  __builtin_amdgcn_global_load_lds(
      (const __attribute__((address_space(1))) void*)g,
      (__attribute__((address_space(3))) void*)l, 16, 0, 0);
}
__device__ __forceinline__ bf16x8 ldsread(const unsigned short* p) {
  return *reinterpret_cast<const bf16x8*>(p);
}

// ---------------------------------------------------------------------------
// x (fp32 [M][K]) -> x_hi, x_lo (bf16 [M][K])
// ---------------------------------------------------------------------------
__global__ __launch_bounds__(256)
void convert_x_k(const float* __restrict__ x, unsigned short* __restrict__ xh,
                 unsigned short* __restrict__ xl) {
  size_t i = ((size_t)blockIdx.x * 256 + threadIdx.x) * 4;
  float4 v = *reinterpret_cast<const float4*>(&x[i]);
  float f[4] = {v.x, v.y, v.z, v.w};
  unsigned short hh[4], ll[4];
#pragma unroll
  for (int j = 0; j < 4; ++j) {
    hh[j] = f2bf(f[j]);
    ll[j] = f2bf(f[j] - bf2f(hh[j]));
  }
  uint2 ph, pl;
  ph.x = hh[0] | ((unsigned)hh[1] << 16); ph.y = hh[2] | ((unsigned)hh[3] << 16);
  pl.x = ll[0] | ((unsigned)ll[1] << 16); pl.y = ll[2] | ((unsigned)ll[3] << 16);
  *reinterpret_cast<uint2*>(&xh[i]) = ph;
  *reinterpret_cast<uint2*>(&xl[i]) = pl;
}

// ---------------------------------------------------------------------------
// W (fp32 [K=2048][N]) -> W^T hi/lo (bf16 [rowOff+N][2048])
// ---------------------------------------------------------------------------
__global__ __launch_bounds__(256)
void convert_wT_k(const float* __restrict__ W, int N, int rowOff,
                  unsigned short* __restrict__ wTh,
                  unsigned short* __restrict__ wTl) {
  __shared__ float tile[32][33];
  const int k0 = blockIdx.y * 32;
  const int n0 = blockIdx.x * 32;
  const int tid = threadIdx.x;
  {
    int r = tid >> 3, c4 = (tid & 7) * 4;
    float4 v = *reinterpret_cast<const float4*>(&W[(size_t)(k0 + r) * N + n0 + c4]);
    tile[r][c4 + 0] = v.x; tile[r][c4 + 1] = v.y;
    tile[r][c4 + 2] = v.z; tile[r][c4 + 3] = v.w;
  }
  __syncthreads();
  int n = tid >> 3, kc = (tid & 7) * 4;
  unsigned short hh[4], ll[4];
#pragma unroll
  for (int j = 0; j < 4; ++j) {
    float f = tile[kc + j][n];
    hh[j] = f2bf(f);
    ll[j] = f2bf(f - bf2f(hh[j]));
  }
  size_t o = (size_t)(rowOff + n0 + n) * HID + k0 + kc;
  uint2 ph, pl;
  ph.x = hh[0] | ((unsigned)hh[1] << 16); ph.y = hh[2] | ((unsigned)hh[3] << 16);
  pl.x = ll[0] | ((unsigned)ll[1] << 16); pl.y = ll[2] | ((unsigned)ll[3] << 16);
  *reinterpret_cast<uint2*>(&wTh[o]) = ph;
  *reinterpret_cast<uint2*>(&wTl[o]) = pl;
}

// ---------------------------------------------------------------------------
// Split-bf16 GEMM: C = relu(A@W + b), A = Ah+Al, B^T = Bh+Bl (bf16 splits)
//   C = Ah@Bh + Ah@Bl + Al@Bh   (fp32 accum; lo*lo dropped ~2^-18)
// Block tile 256x256, BK=32, 512 thr (8 waves, 2M x 4N), WAVE-TILE 128x64
// (65 FLOP/LDS-byte -> MFMA is the long pole, 1.5x over LDS pipe).
// LDS: double buffer 2 x 64KB = 128 KB. Pipeline per K-tile:
//   compute(buf) | barrier | stage(t+2 -> just-freed buf) | vmcnt(8) | barrier
// (t+1's 8 loads/thread hide under a full compute phase; never vmcnt(0)).
// Slot-XOR swizzle both-sides (PMC-verified 0 conflicts, r3).
// Blocks >= NCOMP are pure zerofill (disp+comb) co-running in generation 2.
// ---------------------------------------------------------------------------
__global__ __launch_bounds__(512, 2)
void gemm_split_k(const unsigned short* __restrict__ Ahg,
                  const unsigned short* __restrict__ Alg,
                  const unsigned short* __restrict__ Bhg,
                  const unsigned short* __restrict__ Blg,
                  const float* __restrict__ bi1, const float* __restrict__ br1,
                  const float* __restrict__ bu1, float* __restrict__ h_i,
                  float* __restrict__ h_r, float* __restrict__ h_u,
                  float* __restrict__ dzero) {
  const int bid = blockIdx.x;
  const int tid = threadIdx.x;

  // ---- co-dispatched zerofill blocks (no barriers, fill gen-2 idle CUs)
  if (bid >= NCOMP) {
    if (dzero) {
      f32x4 z = (f32x4){0.f, 0.f, 0.f, 0.f};
      f32x4* d4 = (f32x4*)dzero;
      for (size_t i = (size_t)(bid - NCOMP) * 512 + tid; i < ZTOT4;
           i += (size_t)NZERO * 512)
        __builtin_nontemporal_store(z, d4 + i);
    }
    return;
  }

  // buf layout (shorts): Ah@0(8192) Al@8192 Bh@16384 Bl@24576 -> 32768/buf
  __shared__ unsigned short lds[65536];          // 2 x 32768 shorts = 128 KB
  const int lane = tid & 63;
  const int wave = tid >> 6;
  const int lr   = lane & 15;
  const int slot = lane >> 4;                    // k-slot 0..3

  // XCD-chunked bijective swizzle (320 % 8 == 0)
  const int swz = (bid & 7) * 40 + (bid >> 3);
  const int mt  = swz & 15;                      // 0..15 (M panel of 256)
  const int nt  = swz >> 4;                      // 0..19 (N panel of 256)
  const int row0  = mt * 256;
  const int bcol0 = nt * 256;

  // ---- staging map: 8 x 16B chunks per thread per K-tile (64KB total)
  const unsigned short* gsrc[8];
  int ldsoff[8];
#pragma unroll
  for (int j = 0; j < 8; ++j) {
    int c = (wave * 8 + j) * 64 + lane;          // 0..4095
    int section = c >> 10;                       // 0:Ah 1:Al 2:Bh 3:Bl
    int idx = c & 1023;                          // 256 rows x 4 slots
    int r = idx >> 2, q = idx & 3;
    int qs = q ^ ((r >> 1) & 3);                 // pre-swizzled source slot
    const unsigned short* base = (section == 0) ? Ahg :
                                 (section == 1) ? Alg :
                                 (section == 2) ? Bhg : Blg;
    int rowg = ((section < 2) ? row0 : bcol0) + r;
    gsrc[j] = base + (size_t)rowg * HID + qs * 8;
    ldsoff[j] = c * 8;                           // linear LDS dest (shorts)
  }

  // ---- ds_read offsets (swizzled, conflict-free)
  int aoff[8], boff[4];
#pragma unroll
  for (int m = 0; m < 8; ++m) {
    int ra = (wave >> 2) * 128 + m * 16 + lr;    // 0..255
    aoff[m] = ra * 32 + (slot ^ ((ra >> 1) & 3)) * 8;
  }
#pragma unroll
  for (int n = 0; n < 4; ++n) {
    int rb = (wave & 3) * 64 + n * 16 + lr;      // 0..255
    boff[n] = rb * 32 + (slot ^ ((rb >> 1) & 3)) * 8;
  }

  f32x4 acc[8][4];
#pragma unroll
  for (int m = 0; m < 8; ++m)
#pragma unroll
    for (int n = 0; n < 4; ++n) acc[m][n] = (f32x4){0.f, 0.f, 0.f, 0.f};

  auto stage = [&](int kt, unsigned short* bufbase) {
#pragma unroll
    for (int j = 0; j < 8; ++j)
      gload16(gsrc[j] + kt * 32, bufbase + ldsoff[j]);
  };
  // compute one K-tile: B frags once, walk m 0..7 (compiler pipelines the
  // next-m ds_reads under the current 12-MFMA cluster — no barriers inside)
  auto computeTile = [&](const unsigned short* bb) {
    bf16x8 bvh[4], bvl[4];
#pragma unroll
    for (int n = 0; n < 4; ++n) {
      bvh[n] = ldsread(&bb[16384 + boff[n]]);
      bvl[n] = ldsread(&bb[24576 + boff[n]]);
    }
#pragma unroll
    for (int m = 0; m < 8; ++m) {
      bf16x8 ah = ldsread(&bb[aoff[m]]);
      bf16x8 al = ldsread(&bb[8192 + aoff[m]]);
      __builtin_amdgcn_s_setprio(1);
#pragma unroll
      for (int n = 0; n < 4; ++n) {
        acc[m][n] = __builtin_amdgcn_mfma_f32_16x16x32_bf16(ah, bvh[n], acc[m][n], 0, 0, 0);
        acc[m][n] = __builtin_amdgcn_mfma_f32_16x16x32_bf16(ah, bvl[n], acc[m][n], 0, 0, 0);
        acc[m][n] = __builtin_amdgcn_mfma_f32_16x16x32_bf16(al, bvh[n], acc[m][n], 0, 0, 0);
      }
      __builtin_amdgcn_s_setprio(0);
    }
  };

  unsigned short* pcur = &lds[0];
  unsigned short* pnxt = &lds[32768];

  // prologue: tiles 0,1 in flight; tile 0 landed (8 newest = tile 1's)
  stage(0, pcur);
  stage(1, pnxt);
  asm volatile("s_waitcnt vmcnt(8)" ::: "memory");
  __builtin_amdgcn_s_barrier();
  __builtin_amdgcn_sched_barrier(0);

  // steady state: 64 K-tiles; stage t+2 into the buffer just freed by t
#pragma unroll 1
  for (int t = 0; t < 62; ++t) {
    computeTile(pcur);                               // tile t
    __builtin_amdgcn_s_barrier();                    // all reads of pcur done
    stage(t + 2, pcur);                              // t+2 -> freed buffer
    asm volatile("s_waitcnt vmcnt(8)" ::: "memory"); // t+1 landed; t+2 flying
    __builtin_amdgcn_s_barrier();
    __builtin_amdgcn_sched_barrier(0);
    unsigned short* tmp = pcur; pcur = pnxt; pnxt = tmp;
  }
  computeTile(pcur);                                 // tile 62
  __builtin_amdgcn_s_barrier();
  asm volatile("s_waitcnt vmcnt(0)" ::: "memory");   // tile 63 landed
  __builtin_amdgcn_s_barrier();
  computeTile(pnxt);                                 // tile 63

  // ---- epilogue: bias + relu + store
  float* C; const float* bias; int ldc, col0l;
  if (nt < 4)       { C = h_i; bias = bi1; ldc = 1024; col0l = nt * 256; }
  else if (nt < 12) { C = h_r; bias = br1; ldc = 2048; col0l = (nt - 4) * 256; }
  else              { C = h_u; bias = bu1; ldc = 2048; col0l = (nt - 12) * 256; }
#pragma unroll
  for (int n = 0; n < 4; ++n) {
    int cg = col0l + (wave & 3) * 64 + n * 16 + lr;
    float bn = bias[cg];
#pragma unroll
    for (int m = 0; m < 8; ++m) {
      int rbase = row0 + (wave >> 2) * 128 + m * 16 + slot * 4;
#pragma unroll
      for (int j = 0; j < 4; ++j)
        C[(size_t)(rbase + j) * ldc + cg] = fmaxf(acc[m][n][j] + bn, 0.f);
    }
  }
}

// ---------------------------------------------------------------------------
// Per-token second layers + softmax + top-1 flag. One block per token.
// ---------------------------------------------------------------------------
__global__ __launch_bounds__(256)
void router_k(const float* __restrict__ h_i, const float* __restrict__ h_r,
              const float* __restrict__ h_u,
              const float* __restrict__ Wi2, const float* __restrict__ bi2,
              const float* __restrict__ Wr2, const float* __restrict__ br2,
              const float* __restrict__ Wu2, const float* __restrict__ bu2,
              float* __restrict__ router_probs, float* __restrict__ importance,
              int* __restrict__ expert_used) {
  const int t = blockIdx.x;
  const int tid = threadIdx.x;

  float acc_i;
  {
    float4 hv = *reinterpret_cast<const float4*>(&h_i[(size_t)t * 1024 + tid * 4]);
    float4 wv = *reinterpret_cast<const float4*>(&Wi2[tid * 4]);
    acc_i = hv.x * wv.x + hv.y * wv.y + hv.z * wv.z + hv.w * wv.w;
  }

  float accR[8], accU[8];
#pragma unroll
  for (int e = 0; e < 8; ++e) { accR[e] = 0.f; accU[e] = 0.f; }

  const int i0 = tid * 8;
  {
    float4 h0 = *reinterpret_cast<const float4*>(&h_r[(size_t)t * 2048 + i0]);
    float4 h1 = *reinterpret_cast<const float4*>(&h_r[(size_t)t * 2048 + i0 + 4]);
    float hr[8] = {h0.x, h0.y, h0.z, h0.w, h1.x, h1.y, h1.z, h1.w};
#pragma unroll
    for (int q = 0; q < 8; ++q) {
      float4 w0 = *reinterpret_cast<const float4*>(&Wr2[(size_t)(i0 + q) * 8]);
      float4 w1 = *reinterpret_cast<const float4*>(&Wr2[(size_t)(i0 + q) * 8 + 4]);
      accR[0] = fmaf(hr[q], w0.x, accR[0]); accR[1] = fmaf(hr[q], w0.y, accR[1]);
      accR[2] = fmaf(hr[q], w0.z, accR[2]); accR[3] = fmaf(hr[q], w0.w, accR[3]);
      accR[4] = fmaf(hr[q], w1.x, accR[4]); accR[5] = fmaf(hr[q], w1.y, accR[5]);
      accR[6] = fmaf(hr[q], w1.z, accR[6]); accR[7] = fmaf(hr[q], w1.w, accR[7]);
    }
  }
  {
    float4 h0 = *reinterpret_cast<const float4*>(&h_u[(size_t)t * 2048 + i0]);
    float4 h1 = *reinterpret_cast<const float4*>(&h_u[(size_t)t * 2048 + i0 + 4]);
    float hu[8] = {h0.x, h0.y, h0.z, h0.w, h1.x, h1.y, h1.z, h1.w};
#pragma unroll
    for (int q = 0; q < 8; ++q) {
      float4 w0 = *reinterpret_cast<const float4*>(&Wu2[(size_t)(i0 + q) * 8]);
      float4 w1 = *reinterpret_cast<const float4*>(&Wu2[(size_t)(i0 + q) * 8 + 4]);
      accU[0] = fmaf(hu[q], w0.x, accU[0]); accU[1] = fmaf(hu[q], w0.y, accU[1]);
      accU[2] = fmaf(hu[q], w0.z, accU[2]); accU[3] = fmaf(hu[q], w0.w, accU[3]);
      accU[4] = fmaf(hu[q], w1.x, accU[4]); accU[5] = fmaf(hu[q], w1.y, accU[5]);
      accU[6] = fmaf(hu[q], w1.z, accU[6]); accU[7] = fmaf(hu[q], w1.w, accU[7]);
    }
  }

  float vals[17];
  vals[0] = acc_i;
#pragma unroll
  for (int e = 0; e < 8; ++e) { vals[1 + e] = accR[e]; vals[9 + e] = accU[e]; }
#pragma unroll
  for (int k = 0; k < 17; ++k) {
    float v = vals[k];
    v += __shfl_xor(v, 1);  v += __shfl_xor(v, 2);  v += __shfl_xor(v, 4);
    v += __shfl_xor(v, 8);  v += __shfl_xor(v, 16); v += __shfl_xor(v, 32);
    vals[k] = v;
  }
  __shared__ float red[4][17];
  const int lane = tid & 63, wid = tid >> 6;
  if (lane == 0) {
#pragma unroll
    for (int k = 0; k < 17; ++k) red[wid][k] = vals[k];
  }
  __syncthreads();
  if (tid == 0) {
    float s[17];
#pragma unroll
    for (int k = 0; k < 17; ++k)
      s[k] = red[0][k] + red[1][k] + red[2][k] + red[3][k];
    float imp = 1.f / (1.f + expf(-(s[0] + bi2[0])));
    importance[t] = imp;
    bool useImp = imp > 0.5f;
    float logits[8];
#pragma unroll
    for (int e = 0; e < 8; ++e)
      logits[e] = useImp ? (s[1 + e] + br2[e]) : (s[9 + e] + bu2[e]);
    float mx = logits[0];
#pragma unroll
    for (int e = 1; e < 8; ++e) mx = fmaxf(mx, logits[e]);
    float ex[8], sum = 0.f;
#pragma unroll
    for (int e = 0; e < 8; ++e) { ex[e] = expf(logits[e] - mx); sum += ex[e]; }
    float p[8];
#pragma unroll
    for (int e = 0; e < 8; ++e) p[e] = ex[e] / sum;
#pragma unroll
    for (int e = 0; e < 8; ++e) router_probs[(size_t)t * 8 + e] = p[e];
    int e1 = 0; float p1 = p[0];
#pragma unroll
    for (int e = 1; e < 8; ++e) if (p[e] > p1) { p1 = p[e]; e1 = e; }
    expert_used[e1] = 1;   // benign race: all writers store 1
  }
}

// ---------------------------------------------------------------------------
__global__ __launch_bounds__(256)
void scatter_k(const float* __restrict__ router_probs,
               const int* __restrict__ expert_used,
               float* __restrict__ disp, float* __restrict__ comb) {
  int t = blockIdx.x * blockDim.x + threadIdx.x;
  if (t >= M_TOK) return;
  float4 a = *reinterpret_cast<const float4*>(&router_probs[(size_t)t * 8]);
  float4 b = *reinterpret_cast<const float4*>(&router_probs[(size_t)t * 8 + 4]);
  float p[8] = {a.x, a.y, a.z, a.w, b.x, b.y, b.z, b.w};
  int e1 = 0; float p1 = p[0];
#pragma unroll
  for (int e = 1; e < 8; ++e) if (p[e] > p1) { p1 = p[e]; e1 = e; }
  int e2 = 0; float p2 = -1.f;
#pragma unroll
  for (int e = 0; e < 8; ++e) {
    if (e == e1) continue;
    if (p[e] > p2) { p2 = p[e]; e2 = e; }
  }
  float s = p1 + p2;
  float p1n = p1 / s, p2n = p2 / s;
  size_t base = (size_t)t * NEXP * CAP;
  disp[base + (size_t)e1 * CAP + 0] = 1.f;
  comb[base + (size_t)e1 * CAP + 0] = p1n;
  int pos = expert_used[e2];
  disp[base + (size_t)e2 * CAP + pos] = 1.f;
  comb[base + (size_t)e2 * CAP + pos] = p2n;
}

// ---------------------------------------------------------------------------
// Aux loss + zero the flag tail (runs after scatter).
// ---------------------------------------------------------------------------
__global__ __launch_bounds__(256)
void aux_k(const float* __restrict__ router_probs,
           const float* __restrict__ importance, float* __restrict__ aux_out,
           float* __restrict__ flag_tail) {
  const int tid = threadIdx.x;
  if (tid < 16) flag_tail[tid] = 0.f;
  float s8[8], m8[8];
#pragma unroll
  for (int e = 0; e < 8; ++e) { s8[e] = 0.f; m8[e] = 0.f; }
  for (int t = tid; t < M_TOK; t += 256) {
    float4 a = *reinterpret_cast<const float4*>(&router_probs[(size_t)t * 8]);
    float4 b = *reinterpret_cast<const float4*>(&router_probs[(size_t)t * 8 + 4]);
    float mk = importance[t] > 0.5f ? 1.f : 0.f;
    s8[0] += a.x; s8[1] += a.y; s8[2] += a.z; s8[3] += a.w;
    s8[4] += b.x; s8[5] += b.y; s8[6] += b.z; s8[7] += b.w;
    m8[0] += a.x * mk; m8[1] += a.y * mk; m8[2] += a.z * mk; m8[3] += a.w * mk;
    m8[4] += b.x * mk; m8[5] += b.y * mk; m8[6] += b.z * mk; m8[7] += b.w * mk;
  }
  float vals[16];
#pragma unroll
  for (int e = 0; e < 8; ++e) { vals[e] = s8[e]; vals[8 + e] = m8[e]; }
#pragma unroll
  for (int k = 0; k < 16; ++k) {
    float v = vals[k];
    v += __shfl_xor(v, 1);  v += __shfl_xor(v, 2);  v += __shfl_xor(v, 4);
    v += __shfl_xor(v, 8);  v += __shfl_xor(v, 16); v += __shfl_xor(v, 32);
    vals[k] = v;
  }
  __shared__ float red[4][16];
  const int lane = tid & 63, wid = tid >> 6;
  if (lane == 0) {
#pragma unroll
    for (int k = 0; k < 16; ++k) red[wid][k] = vals[k];
  }
  __syncthreads();
  if (tid == 0) {
    float s[16];
#pragma unroll
    for (int k = 0; k < 16; ++k)
      s[k] = red[0][k] + red[1][k] + red[2][k] + red[3][k];
    float entropy_loss = 0.f;
#pragma unroll
    for (int e = 0; e < 8; ++e) {
      float rppe = s[e] / (float)M_TOK;
      entropy_loss += rppe * logf(rppe * 8.f + 1e-9f);
    }
    float tot = 0.f;
#pragma unroll
    for (int e = 0; e < 8; ++e) tot += s[8 + e] + 1e-9f;
    float imp_entropy = 0.f;
#pragma unroll
    for (int e = 0; e < 8; ++e) {
      float ipe = (s[8 + e] + 1e-9f) / tot;
      imp_entropy -= ipe * logf(ipe + 1e-9f);
    }
    aux_out[0] = entropy_loss - 0.1f * (imp_entropy / logf(8.f));
  }
}

// ---------------------------------------------------------------------------
extern "C" void kernel_launch(void* const* d_in, const int* in_sizes, int n_in,
                              void* d_out, int out_size, void* d_ws,
                              size_t ws_size, hipStream_t stream) {
  const float* x   = (const float*)d_in[0];
  const float* Wi1 = (const float*)d_in[1];
  const float* bi1 = (const float*)d_in[2];
  const float* Wi2 = (const float*)d_in[3];
  const float* bi2 = (const float*)d_in[4];
  const float* Wr1 = (const float*)d_in[5];
  const float* br1 = (const float*)d_in[6];
  const float* Wr2 = (const float*)d_in[7];
  const float* br2 = (const float*)d_in[8];
  const float* Wu1 = (const float*)d_in[9];
  const float* bu1 = (const float*)d_in[10];
  const float* Wu2 = (const float*)d_in[11];
  const float* bu2 = (const float*)d_in[12];

  float* out  = (float*)d_out;
  float* disp = out;
  float* comb = out + DISP_ELEMS;
  float* rp   = out + 2 * DISP_ELEMS;            // 32768
  float* aux  = out + 2 * DISP_ELEMS + 32768;    // 1
  float* imp  = aux + 1;                         // 4096

  // scratch layout (bytes):
  //   xh 16.78M | xl 16.78M | wTh 20.97M | wTl 20.97M | h_i 16.78M | h_r 33.55M | h_u 33.55M
  const size_t xh_b  = (size_t)M_TOK * HID * 2;
  const size_t wT_b  = (size_t)NTOT * HID * 2;
  const size_t hi_b  = (size_t)M_TOK * 1024 * 4;
  const size_t hr_b  = (size_t)M_TOK * 2048 * 4;
  const size_t need  = 2 * xh_b + 2 * wT_b + hi_b + 2 * hr_b + 256;
  const bool ws_ok = (ws_size >= need);
  char* scratch = ws_ok ? (char*)d_ws : (char*)comb;  // comb region 201MB > 153MB

  unsigned short* xh  = (unsigned short*)scratch;
  unsigned short* xl  = (unsigned short*)(scratch + xh_b);
  unsigned short* wTh = (unsigned short*)(scratch + 2 * xh_b);
  unsigned short* wTl = (unsigned short*)(scratch + 2 * xh_b + wT_b);
  float* h_i = (float*)(scratch + 2 * xh_b + 2 * wT_b);
  float* h_r = h_i + (size_t)M_TOK * 1024;
  float* h_u = h_r + (size_t)M_TOK * 2048;
  int* flags = (int*)(comb + DISP_ELEMS - 16);

  // 1. zeroing: if ws_ok, the co-dispatched zerofill blocks inside gemm
  //    cover disp+comb (incl. flag tail). Otherwise fall back to memsets.
  if (!ws_ok) {
    (void)hipMemsetAsync(disp, 0, DISP_ELEMS * sizeof(float), stream);
    (void)hipMemsetAsync(flags, 0, 16 * sizeof(float), stream);
  }

  // 2. convert inputs to bf16 hi/lo (W transposed into concat [5120][2048])
  convert_x_k<<<(M_TOK * HID / 4) / 256, 256, 0, stream>>>(x, xh, xl);
  convert_wT_k<<<dim3(1024 / 32, HID / 32), 256, 0, stream>>>(Wi1, 1024, 0, wTh, wTl);
  convert_wT_k<<<dim3(2048 / 32, HID / 32), 256, 0, stream>>>(Wr1, 2048, 1024, wTh, wTl);
  convert_wT_k<<<dim3(2048 / 32, HID / 32), 256, 0, stream>>>(Wu1, 2048, 3072, wTh, wTl);

  // 3. fused split-bf16 MFMA GEMM: 320 compute + 192 zerofill blocks
  const int nblocks = ws_ok ? (NCOMP + NZERO) : NCOMP;
  gemm_split_k<<<nblocks, 512, 0, stream>>>(xh, xl, wTh, wTl, bi1, br1, bu1,
                                            h_i, h_r, h_u,
                                            ws_ok ? disp : (float*)nullptr);

  // 4. router probs / importance / top-1 flags
  router_k<<<M_TOK, 256, 0, stream>>>(h_i, h_r, h_u, Wi2, bi2, Wr2, br2,
                                      Wu2, bu2, rp, imp, flags);

  // 5. zero comb if it was used as scratch (keep flag tail, just written)
  if (!ws_ok)
    (void)hipMemsetAsync(comb, 0, (DISP_ELEMS - 16) * sizeof(float), stream);

  // 6. scatter the 2 nonzeros per token
  scatter_k<<<(M_TOK + 255) / 256, 256, 0, stream>>>(rp, flags, disp, comb);

  // 7. aux loss + flag-tail zeroing
  aux_k<<<1, 256, 0, stream>>>(rp, imp, aux, (float*)flags);
}

// Round 8
// 387.409 us; speedup vs baseline: 1.1932x; 1.1932x over previous
//
#include <hip/hip_runtime.h>
#include <math.h>

#define M_TOK 4096           // B*S
#define HID   2048
#define NEXP  8
#define CAP   1536
#define DISP_ELEMS 50331648ull   // 4096*8*1536
#define NTOT  5120               // 1024 + 2048 + 2048 (concat N)
#define ZTOT4 25165824ull        // (2*DISP_ELEMS)/4 float4s
#define NCOMP 640                // compute blocks (32 M x 20 N), 128x256 tiles
#define NZERO 128                // zerofill blocks; 640+128 = 768 = 3*256

typedef __attribute__((ext_vector_type(8))) short bf16x8;
typedef __attribute__((ext_vector_type(4))) float f32x4;

__device__ __forceinline__ unsigned short f2bf(float f) {
  unsigned u = __float_as_uint(f);
  unsigned r = u + 0x7FFFu + ((u >> 16) & 1u);   // RNE (finite inputs)
  return (unsigned short)(r >> 16);
}
__device__ __forceinline__ float bf2f(unsigned short h) {
  return __uint_as_float(((unsigned)h) << 16);
}

__device__ __forceinline__ void gload16(const void* g, void* l) {
  __builtin_amdgcn_global_load_lds(
      (const __attribute__((address_space(1))) void*)g,
      (__attribute__((address_space(3))) void*)l, 16, 0, 0);
}
__device__ __forceinline__ bf16x8 ldsread(const unsigned short* p) {
  return *reinterpret_cast<const bf16x8*>(p);
}

// ---------------------------------------------------------------------------
// x (fp32 [M][K]) -> x_hi, x_lo (bf16 [M][K])
// ---------------------------------------------------------------------------
__global__ __launch_bounds__(256)
void convert_x_k(const float* __restrict__ x, unsigned short* __restrict__ xh,
                 unsigned short* __restrict__ xl) {
  size_t i = ((size_t)blockIdx.x * 256 + threadIdx.x) * 4;
  float4 v = *reinterpret_cast<const float4*>(&x[i]);
  float f[4] = {v.x, v.y, v.z, v.w};
  unsigned short hh[4], ll[4];
#pragma unroll
  for (int j = 0; j < 4; ++j) {
    hh[j] = f2bf(f[j]);
    ll[j] = f2bf(f[j] - bf2f(hh[j]));
  }
  uint2 ph, pl;
  ph.x = hh[0] | ((unsigned)hh[1] << 16); ph.y = hh[2] | ((unsigned)hh[3] << 16);
  pl.x = ll[0] | ((unsigned)ll[1] << 16); pl.y = ll[2] | ((unsigned)ll[3] << 16);
  *reinterpret_cast<uint2*>(&xh[i]) = ph;
  *reinterpret_cast<uint2*>(&xl[i]) = pl;
}

// ---------------------------------------------------------------------------
// W (fp32 [K=2048][N]) -> W^T hi/lo (bf16 [rowOff+N][2048])
// ---------------------------------------------------------------------------
__global__ __launch_bounds__(256)
void convert_wT_k(const float* __restrict__ W, int N, int rowOff,
                  unsigned short* __restrict__ wTh,
                  unsigned short* __restrict__ wTl) {
  __shared__ float tile[32][33];
  const int k0 = blockIdx.y * 32;
  const int n0 = blockIdx.x * 32;
  const int tid = threadIdx.x;
  {
    int r = tid >> 3, c4 = (tid & 7) * 4;
    float4 v = *reinterpret_cast<const float4*>(&W[(size_t)(k0 + r) * N + n0 + c4]);
    tile[r][c4 + 0] = v.x; tile[r][c4 + 1] = v.y;
    tile[r][c4 + 2] = v.z; tile[r][c4 + 3] = v.w;
  }
  __syncthreads();
  int n = tid >> 3, kc = (tid & 7) * 4;
  unsigned short hh[4], ll[4];
#pragma unroll
  for (int j = 0; j < 4; ++j) {
    float f = tile[kc + j][n];
    hh[j] = f2bf(f);
    ll[j] = f2bf(f - bf2f(hh[j]));
  }
  size_t o = (size_t)(rowOff + n0 + n) * HID + k0 + kc;
  uint2 ph, pl;
  ph.x = hh[0] | ((unsigned)hh[1] << 16); ph.y = hh[2] | ((unsigned)hh[3] << 16);
  pl.x = ll[0] | ((unsigned)ll[1] << 16); pl.y = ll[2] | ((unsigned)ll[3] << 16);
  *reinterpret_cast<uint2*>(&wTh[o]) = ph;
  *reinterpret_cast<uint2*>(&wTl[o]) = pl;
}

// ---------------------------------------------------------------------------
// Split-bf16 GEMM, deep-pipelined (r4-proven structure):
//   C = relu(A@W + b) with A = Ah+Al, B^T = Bh+Bl (bf16 splits)
//   C = Ah@Bh + Ah@Bl + Al@Bh   (fp32 accum; lo*lo dropped ~2^-18)
// BM=128, BN=256, BK=32, 512 threads (8 waves, 2M x 4N), per-wave 64x64.
// LDS: TRIPLE buffer x 48KB = 144 KB. One barrier pair per K-tile; steady
// wait vmcnt(6) (tile t+2's 6 loads/thread stay in flight) -- never 0.
// Slot-XOR swizzle both sides (PMC-verified 0 conflicts, r3).
// Blocks >= NCOMP are pure zerofill for disp+comb: 640+128 = 768 = 3x256,
// so zerofill lands in generation 3 on the CUs compute leaves idle.
// ---------------------------------------------------------------------------
__global__ __launch_bounds__(512)
void gemm_split_k(const unsigned short* __restrict__ Ahg,
                  const unsigned short* __restrict__ Alg,
                  const unsigned short* __restrict__ Bhg,
                  const unsigned short* __restrict__ Blg,
                  const float* __restrict__ bi1, const float* __restrict__ br1,
                  const float* __restrict__ bu1, float* __restrict__ h_i,
                  float* __restrict__ h_r, float* __restrict__ h_u,
                  float* __restrict__ dzero) {
  const int bid = blockIdx.x;
  const int tid = threadIdx.x;

  // ---- dedicated zerofill blocks (generation 3 filler)
  if (bid >= NCOMP) {
    if (dzero) {
      f32x4 z = (f32x4){0.f, 0.f, 0.f, 0.f};
      f32x4* d4 = (f32x4*)dzero;
      for (size_t i = (size_t)(bid - NCOMP) * 512 + tid; i < ZTOT4;
           i += (size_t)NZERO * 512)
        __builtin_nontemporal_store(z, d4 + i);
    }
    return;
  }

  // buf layout (shorts): Ah@0(4096) Al@4096 Bh@8192(8192) Bl@16384 -> 24576
  __shared__ unsigned short lds[73728];          // 3 x 24576 shorts = 144 KB
  const int lane = tid & 63;
  const int wave = tid >> 6;
  const int lr   = lane & 15;
  const int slot = lane >> 4;                    // k-slot 0..3

  // XCD-chunked bijective swizzle (640 % 8 == 0)
  const int swz = (bid & 7) * 80 + (bid >> 3);
  const int nt  = swz >> 5;                      // 0..19 (N panel of 256)
  const int mt  = swz & 31;                      // 0..31 (M panel of 128)
  const int row0  = mt * 128;
  const int bcol0 = nt * 256;

  // ---- per-thread staging sources (6 x 16B chunks per thread per K-tile)
  const unsigned short* gsrc[6];
  int ldsoff[6];
#pragma unroll
  for (int j = 0; j < 6; ++j) {
    int c = (wave * 6 + j) * 64 + lane;          // 0..3071
    int idx, r;
    const unsigned short* base;
    size_t rowbase;
    if (c < 1024) {                              // A hi/lo: 128 rows x 4 slots
      idx = c & 511; r = idx >> 2;
      base = (c < 512) ? Ahg : Alg;
      rowbase = (size_t)(row0 + r) * HID;
    } else {                                     // B hi/lo: 256 rows x 4 slots
      idx = (c - 1024) & 1023; r = idx >> 2;
      base = (c < 2048) ? Bhg : Blg;
      rowbase = (size_t)(bcol0 + r) * HID;
    }
    int q  = idx & 3;
    int qs = q ^ ((r >> 1) & 3);                 // pre-swizzled source slot
    gsrc[j] = base + rowbase + qs * 8;
    ldsoff[j] = c * 8;                           // linear LDS dest (shorts)
  }

  // ---- per-thread ds_read offsets (swizzled, conflict-free per r3 PMC)
  int aoff[4], boff[4];
#pragma unroll
  for (int m = 0; m < 4; ++m) {
    int ra = (wave >> 2) * 64 + m * 16 + lr;     // 0..127
    aoff[m] = ra * 32 + (slot ^ ((ra >> 1) & 3)) * 8;
  }
#pragma unroll
  for (int n = 0; n < 4; ++n) {
    int rb = (wave & 3) * 64 + n * 16 + lr;      // 0..255
    boff[n] = rb * 32 + (slot ^ ((rb >> 1) & 3)) * 8;
  }

  f32x4 acc[4][4];
#pragma unroll
  for (int m = 0; m < 4; ++m)
#pragma unroll
    for (int n = 0; n < 4; ++n) acc[m][n] = (f32x4){0.f, 0.f, 0.f, 0.f};

  auto stage = [&](int kt, unsigned short* bufbase) {
#pragma unroll
    for (int j = 0; j < 6; ++j)
      gload16(gsrc[j] + kt * 32, bufbase + ldsoff[j]);
  };
  auto computeTile = [&](const unsigned short* bb) {
    bf16x8 avh[4], avl[4], bvh[4], bvl[4];
#pragma unroll
    for (int m = 0; m < 4; ++m) {
      avh[m] = ldsread(&bb[aoff[m]]);
      avl[m] = ldsread(&bb[4096 + aoff[m]]);
    }
#pragma unroll
    for (int n = 0; n < 4; ++n) {
      bvh[n] = ldsread(&bb[8192 + boff[n]]);
      bvl[n] = ldsread(&bb[16384 + boff[n]]);
    }
    __builtin_amdgcn_s_setprio(1);
#pragma unroll
    for (int m = 0; m < 4; ++m)
#pragma unroll
      for (int n = 0; n < 4; ++n) {
        acc[m][n] = __builtin_amdgcn_mfma_f32_16x16x32_bf16(avh[m], bvh[n], acc[m][n], 0, 0, 0);
        acc[m][n] = __builtin_amdgcn_mfma_f32_16x16x32_bf16(avh[m], bvl[n], acc[m][n], 0, 0, 0);
        acc[m][n] = __builtin_amdgcn_mfma_f32_16x16x32_bf16(avl[m], bvh[n], acc[m][n], 0, 0, 0);
      }
    __builtin_amdgcn_s_setprio(0);
  };

  unsigned short* pb0 = &lds[0];
  unsigned short* pb1 = &lds[24576];
  unsigned short* pb2 = &lds[49152];

  // prologue: tiles 0 and 1 in flight
  stage(0, pb0);
  stage(1, pb1);
  asm volatile("s_waitcnt vmcnt(6)" ::: "memory");   // tile 0 landed
  __builtin_amdgcn_s_barrier();
  __builtin_amdgcn_sched_barrier(0);

  // steady state: 64 K-tiles total, stage t+2 while computing t
#pragma unroll 1
  for (int t = 0; t < 62; ++t) {
    stage(t + 2, pb2);
    computeTile(pb0);
    asm volatile("s_waitcnt vmcnt(6)" ::: "memory"); // tile t+1 landed; t+2 flying
    __builtin_amdgcn_s_barrier();
    __builtin_amdgcn_sched_barrier(0);
    unsigned short* tmp = pb0; pb0 = pb1; pb1 = pb2; pb2 = tmp;
  }
  // epilogue tiles 62, 63
  computeTile(pb0);
  asm volatile("s_waitcnt vmcnt(0)" ::: "memory");   // tile 63 landed
  __builtin_amdgcn_s_barrier();
  __builtin_amdgcn_sched_barrier(0);
  computeTile(pb1);

  // ---- epilogue: bias + relu + store
  float* C; const float* bias; int ldc, col0l;
  if (nt < 4)       { C = h_i; bias = bi1; ldc = 1024; col0l = nt * 256; }
  else if (nt < 12) { C = h_r; bias = br1; ldc = 2048; col0l = (nt - 4) * 256; }
  else              { C = h_u; bias = bu1; ldc = 2048; col0l = (nt - 12) * 256; }
#pragma unroll
  for (int n = 0; n < 4; ++n) {
    int cg = col0l + (wave & 3) * 64 + n * 16 + lr;
    float bn = bias[cg];
#pragma unroll
    for (int m = 0; m < 4; ++m) {
      int rbase = row0 + (wave >> 2) * 64 + m * 16 + slot * 4;
#pragma unroll
      for (int j = 0; j < 4; ++j)
        C[(size_t)(rbase + j) * ldc + cg] = fmaxf(acc[m][n][j] + bn, 0.f);
    }
  }
}

// ---------------------------------------------------------------------------
// Per-token second layers + softmax + top-1 flag. One block per token.
// ---------------------------------------------------------------------------
__global__ __launch_bounds__(256)
void router_k(const float* __restrict__ h_i, const float* __restrict__ h_r,
              const float* __restrict__ h_u,
              const float* __restrict__ Wi2, const float* __restrict__ bi2,
              const float* __restrict__ Wr2, const float* __restrict__ br2,
              const float* __restrict__ Wu2, const float* __restrict__ bu2,
              float* __restrict__ router_probs, float* __restrict__ importance,
              int* __restrict__ expert_used) {
  const int t = blockIdx.x;
  const int tid = threadIdx.x;

  float acc_i;
  {
    float4 hv = *reinterpret_cast<const float4*>(&h_i[(size_t)t * 1024 + tid * 4]);
    float4 wv = *reinterpret_cast<const float4*>(&Wi2[tid * 4]);
    acc_i = hv.x * wv.x + hv.y * wv.y + hv.z * wv.z + hv.w * wv.w;
  }

  float accR[8], accU[8];
#pragma unroll
  for (int e = 0; e < 8; ++e) { accR[e] = 0.f; accU[e] = 0.f; }

  const int i0 = tid * 8;
  {
    float4 h0 = *reinterpret_cast<const float4*>(&h_r[(size_t)t * 2048 + i0]);
    float4 h1 = *reinterpret_cast<const float4*>(&h_r[(size_t)t * 2048 + i0 + 4]);
    float hr[8] = {h0.x, h0.y, h0.z, h0.w, h1.x, h1.y, h1.z, h1.w};
#pragma unroll
    for (int q = 0; q < 8; ++q) {
      float4 w0 = *reinterpret_cast<const float4*>(&Wr2[(size_t)(i0 + q) * 8]);
      float4 w1 = *reinterpret_cast<const float4*>(&Wr2[(size_t)(i0 + q) * 8 + 4]);
      accR[0] = fmaf(hr[q], w0.x, accR[0]); accR[1] = fmaf(hr[q], w0.y, accR[1]);
      accR[2] = fmaf(hr[q], w0.z, accR[2]); accR[3] = fmaf(hr[q], w0.w, accR[3]);
      accR[4] = fmaf(hr[q], w1.x, accR[4]); accR[5] = fmaf(hr[q], w1.y, accR[5]);
      accR[6] = fmaf(hr[q], w1.z, accR[6]); accR[7] = fmaf(hr[q], w1.w, accR[7]);
    }
  }
  {
    float4 h0 = *reinterpret_cast<const float4*>(&h_u[(size_t)t * 2048 + i0]);
    float4 h1 = *reinterpret_cast<const float4*>(&h_u[(size_t)t * 2048 + i0 + 4]);
    float hu[8] = {h0.x, h0.y, h0.z, h0.w, h1.x, h1.y, h1.z, h1.w};
#pragma unroll
    for (int q = 0; q < 8; ++q) {
      float4 w0 = *reinterpret_cast<const float4*>(&Wu2[(size_t)(i0 + q) * 8]);
      float4 w1 = *reinterpret_cast<const float4*>(&Wu2[(size_t)(i0 + q) * 8 + 4]);
      accU[0] = fmaf(hu[q], w0.x, accU[0]); accU[1] = fmaf(hu[q], w0.y, accU[1]);
      accU[2] = fmaf(hu[q], w0.z, accU[2]); accU[3] = fmaf(hu[q], w0.w, accU[3]);
      accU[4] = fmaf(hu[q], w1.x, accU[4]); accU[5] = fmaf(hu[q], w1.y, accU[5]);
      accU[6] = fmaf(hu[q], w1.z, accU[6]); accU[7] = fmaf(hu[q], w1.w, accU[7]);
    }
  }

  float vals[17];
  vals[0] = acc_i;
#pragma unroll
  for (int e = 0; e < 8; ++e) { vals[1 + e] = accR[e]; vals[9 + e] = accU[e]; }
#pragma unroll
  for (int k = 0; k < 17; ++k) {
    float v = vals[k];
    v += __shfl_xor(v, 1);  v += __shfl_xor(v, 2);  v += __shfl_xor(v, 4);
    v += __shfl_xor(v, 8);  v += __shfl_xor(v, 16); v += __shfl_xor(v, 32);
    vals[k] = v;
  }
  __shared__ float red[4][17];
  const int lane = tid & 63, wid = tid >> 6;
  if (lane == 0) {
#pragma unroll
    for (int k = 0; k < 17; ++k) red[wid][k] = vals[k];
  }
  __syncthreads();
  if (tid == 0) {
    float s[17];
#pragma unroll
    for (int k = 0; k < 17; ++k)
      s[k] = red[0][k] + red[1][k] + red[2][k] + red[3][k];
    float imp = 1.f / (1.f + expf(-(s[0] + bi2[0])));
    importance[t] = imp;
    bool useImp = imp > 0.5f;
    float logits[8];
#pragma unroll
    for (int e = 0; e < 8; ++e)
      logits[e] = useImp ? (s[1 + e] + br2[e]) : (s[9 + e] + bu2[e]);
    float mx = logits[0];
#pragma unroll
    for (int e = 1; e < 8; ++e) mx = fmaxf(mx, logits[e]);
    float ex[8], sum = 0.f;
#pragma unroll
    for (int e = 0; e < 8; ++e) { ex[e] = expf(logits[e] - mx); sum += ex[e]; }
    float p[8];
#pragma unroll
    for (int e = 0; e < 8; ++e) p[e] = ex[e] / sum;
#pragma unroll
    for (int e = 0; e < 8; ++e) router_probs[(size_t)t * 8 + e] = p[e];
    int e1 = 0; float p1 = p[0];
#pragma unroll
    for (int e = 1; e < 8; ++e) if (p[e] > p1) { p1 = p[e]; e1 = e; }
    expert_used[e1] = 1;   // benign race: all writers store 1
  }
}

// ---------------------------------------------------------------------------
// Scatter + aux partial reduction. 16 blocks x 256 thr (one thread per token).
// Partials: 16 floats (sum p[e]; sum p[e]*mask) accumulated via atomicAdd.
// ---------------------------------------------------------------------------
__global__ __launch_bounds__(256)
void scatter_aux_k(const float* __restrict__ router_probs,
                   const int* __restrict__ expert_used,
                   const float* __restrict__ importance,
                   float* __restrict__ disp, float* __restrict__ comb,
                   float* __restrict__ partials) {
  const int tid = threadIdx.x;
  const int t = blockIdx.x * 256 + tid;
  float4 a = *reinterpret_cast<const float4*>(&router_probs[(size_t)t * 8]);
  float4 b = *reinterpret_cast<const float4*>(&router_probs[(size_t)t * 8 + 4]);
  float p[8] = {a.x, a.y, a.z, a.w, b.x, b.y, b.z, b.w};
  int e1 = 0; float p1 = p[0];
#pragma unroll
  for (int e = 1; e < 8; ++e) if (p[e] > p1) { p1 = p[e]; e1 = e; }
  int e2 = 0; float p2 = -1.f;
#pragma unroll
  for (int e = 0; e < 8; ++e) {
    if (e == e1) continue;
    if (p[e] > p2) { p2 = p[e]; e2 = e; }
  }
  float s = p1 + p2;
  size_t base = (size_t)t * NEXP * CAP;
  disp[base + (size_t)e1 * CAP + 0] = 1.f;
  comb[base + (size_t)e1 * CAP + 0] = p1 / s;
  int pos = expert_used[e2];
  disp[base + (size_t)e2 * CAP + pos] = 1.f;
  comb[base + (size_t)e2 * CAP + pos] = p2 / s;

  // ---- aux partials
  float mk = importance[t] > 0.5f ? 1.f : 0.f;
  float vals[16];
#pragma unroll
  for (int e = 0; e < 8; ++e) { vals[e] = p[e]; vals[8 + e] = p[e] * mk; }
#pragma unroll
  for (int k = 0; k < 16; ++k) {
    float v = vals[k];
    v += __shfl_xor(v, 1);  v += __shfl_xor(v, 2);  v += __shfl_xor(v, 4);
    v += __shfl_xor(v, 8);  v += __shfl_xor(v, 16); v += __shfl_xor(v, 32);
    vals[k] = v;
  }
  __shared__ float red[4][16];
  const int lane = tid & 63, wid = tid >> 6;
  if (lane == 0) {
#pragma unroll
    for (int k = 0; k < 16; ++k) red[wid][k] = vals[k];
  }
  __syncthreads();
  if (tid < 16)
    atomicAdd(&partials[tid],
              red[0][tid] + red[1][tid] + red[2][tid] + red[3][tid]);
}

// ---------------------------------------------------------------------------
// Aux finalize from partials; zero partials + flag tail (comb must end 0).
// ---------------------------------------------------------------------------
__global__ __launch_bounds__(64)
void aux_final_k(float* __restrict__ partials, float* __restrict__ aux_out,
                 float* __restrict__ flag_tail) {
  const int tid = threadIdx.x;
  float s[16];
#pragma unroll
  for (int k = 0; k < 16; ++k) s[k] = partials[k];
  if (tid == 0) {
    float entropy_loss = 0.f;
#pragma unroll
    for (int e = 0; e < 8; ++e) {
      float rppe = s[e] / (float)M_TOK;
      entropy_loss += rppe * logf(rppe * 8.f + 1e-9f);
    }
    float tot = 0.f;
#pragma unroll
    for (int e = 0; e < 8; ++e) tot += s[8 + e] + 1e-9f;
    float imp_entropy = 0.f;
#pragma unroll
    for (int e = 0; e < 8; ++e) {
      float ipe = (s[8 + e] + 1e-9f) / tot;
      imp_entropy -= ipe * logf(ipe + 1e-9f);
    }
    aux_out[0] = entropy_loss - 0.1f * (imp_entropy / logf(8.f));
  }
  if (tid < 16) partials[tid] = 0.f;
  if (tid >= 16 && tid < 32) flag_tail[tid - 16] = 0.f;
}

// ---------------------------------------------------------------------------
extern "C" void kernel_launch(void* const* d_in, const int* in_sizes, int n_in,
                              void* d_out, int out_size, void* d_ws,
                              size_t ws_size, hipStream_t stream) {
  const float* x   = (const float*)d_in[0];
  const float* Wi1 = (const float*)d_in[1];
  const float* bi1 = (const float*)d_in[2];
  const float* Wi2 = (const float*)d_in[3];
  const float* bi2 = (const float*)d_in[4];
  const float* Wr1 = (const float*)d_in[5];
  const float* br1 = (const float*)d_in[6];
  const float* Wr2 = (const float*)d_in[7];
  const float* br2 = (const float*)d_in[8];
  const float* Wu1 = (const float*)d_in[9];
  const float* bu1 = (const float*)d_in[10];
  const float* Wu2 = (const float*)d_in[11];
  const float* bu2 = (const float*)d_in[12];

  float* out  = (float*)d_out;
  float* disp = out;
  float* comb = out + DISP_ELEMS;
  float* rp   = out + 2 * DISP_ELEMS;            // 32768
  float* aux  = out + 2 * DISP_ELEMS + 32768;    // 1
  float* imp  = aux + 1;                         // 4096

  // scratch layout (bytes):
  //   xh 16.78M | xl 16.78M | wTh 20.97M | wTl 20.97M | h_i 16.78M | h_r 33.55M | h_u 33.55M
  const size_t xh_b  = (size_t)M_TOK * HID * 2;
  const size_t wT_b  = (size_t)NTOT * HID * 2;
  const size_t hi_b  = (size_t)M_TOK * 1024 * 4;
  const size_t hr_b  = (size_t)M_TOK * 2048 * 4;
  const size_t need  = 2 * xh_b + 2 * wT_b + hi_b + 2 * hr_b + 256;
  const bool ws_ok = (ws_size >= need);
  char* scratch = ws_ok ? (char*)d_ws : (char*)comb;  // comb region 201MB > 153MB

  unsigned short* xh  = (unsigned short*)scratch;
  unsigned short* xl  = (unsigned short*)(scratch + xh_b);
  unsigned short* wTh = (unsigned short*)(scratch + 2 * xh_b);
  unsigned short* wTl = (unsigned short*)(scratch + 2 * xh_b + wT_b);
  float* h_i = (float*)(scratch + 2 * xh_b + 2 * wT_b);
  float* h_r = h_i + (size_t)M_TOK * 1024;
  float* h_u = h_r + (size_t)M_TOK * 2048;
  // comb tail (never scatter-written: max scatter index < DISP_ELEMS-1534):
  //   partials @ -48 (16 floats), flags @ -16 (16 ints)
  int*   flags    = (int*)(comb + DISP_ELEMS - 16);
  float* partials = comb + DISP_ELEMS - 48;

  // 1. zeroing: if ws_ok, the dedicated zerofill blocks inside gemm cover
  //    disp+comb incl. partials+flags. Otherwise fall back to memsets.
  if (!ws_ok) {
    (void)hipMemsetAsync(disp, 0, DISP_ELEMS * sizeof(float), stream);
    (void)hipMemsetAsync(flags, 0, 16 * sizeof(float), stream);
  }

  // 2. convert inputs to bf16 hi/lo (W transposed into concat [5120][2048])
  convert_x_k<<<(M_TOK * HID / 4) / 256, 256, 0, stream>>>(x, xh, xl);
  convert_wT_k<<<dim3(1024 / 32, HID / 32), 256, 0, stream>>>(Wi1, 1024, 0, wTh, wTl);
  convert_wT_k<<<dim3(2048 / 32, HID / 32), 256, 0, stream>>>(Wr1, 2048, 1024, wTh, wTl);
  convert_wT_k<<<dim3(2048 / 32, HID / 32), 256, 0, stream>>>(Wu1, 2048, 3072, wTh, wTl);

  // 3. fused split-bf16 MFMA GEMM: 640 compute + 128 zerofill = 768 = 3x256
  const int nblocks = ws_ok ? (NCOMP + NZERO) : NCOMP;
  gemm_split_k<<<nblocks, 512, 0, stream>>>(xh, xl, wTh, wTl, bi1, br1, bu1,
                                            h_i, h_r, h_u,
                                            ws_ok ? disp : (float*)nullptr);

  // 4. router probs / importance / top-1 flags
  router_k<<<M_TOK, 256, 0, stream>>>(h_i, h_r, h_u, Wi2, bi2, Wr2, br2,
                                      Wu2, bu2, rp, imp, flags);

  // 5. zero comb if it was used as scratch (covers partials; keep flag tail)
  if (!ws_ok)
    (void)hipMemsetAsync(comb, 0, (DISP_ELEMS - 16) * sizeof(float), stream);

  // 6. scatter + aux partial reduction
  scatter_aux_k<<<M_TOK / 256, 256, 0, stream>>>(rp, flags, imp, disp, comb,
                                                 partials);

  // 7. aux finalize + zero partials/flag tail
  aux_final_k<<<1, 64, 0, stream>>>(partials, aux, (float*)flags);
}

// Round 9
// 342.247 us; speedup vs baseline: 1.3507x; 1.1320x over previous
//
#include <hip/hip_runtime.h>
#include <math.h>

#define M_TOK 4096           // B*S
#define HID   2048
#define NEXP  8
#define CAP   1536
#define DISP_ELEMS 50331648ull   // 4096*8*1536
#define NTOT  5120               // 1024 + 2048 + 2048 (concat N)
#define ZTOT4 25165824ull        // (2*DISP_ELEMS)/4 float4s

typedef __attribute__((ext_vector_type(8))) short bf16x8;
typedef __attribute__((ext_vector_type(4))) float f32x4;

__device__ __forceinline__ unsigned short f2bf(float f) {
  unsigned u = __float_as_uint(f);
  unsigned r = u + 0x7FFFu + ((u >> 16) & 1u);   // RNE (finite inputs)
  return (unsigned short)(r >> 16);
}
__device__ __forceinline__ float bf2f(unsigned short h) {
  return __uint_as_float(((unsigned)h) << 16);
}

__device__ __forceinline__ void gload16(const void* g, void* l) {
  __builtin_amdgcn_global_load_lds(
      (const __attribute__((address_space(1))) void*)g,
      (__attribute__((address_space(3))) void*)l, 16, 0, 0);
}
__device__ __forceinline__ bf16x8 ldsread(const unsigned short* p) {
  return *reinterpret_cast<const bf16x8*>(p);
}

// ---------------------------------------------------------------------------
// x (fp32 [M][K]) -> x_hi, x_lo (bf16 [M][K])
// ---------------------------------------------------------------------------
__global__ __launch_bounds__(256)
void convert_x_k(const float* __restrict__ x, unsigned short* __restrict__ xh,
                 unsigned short* __restrict__ xl) {
  size_t i = ((size_t)blockIdx.x * 256 + threadIdx.x) * 4;
  float4 v = *reinterpret_cast<const float4*>(&x[i]);
  float f[4] = {v.x, v.y, v.z, v.w};
  unsigned short hh[4], ll[4];
#pragma unroll
  for (int j = 0; j < 4; ++j) {
    hh[j] = f2bf(f[j]);
    ll[j] = f2bf(f[j] - bf2f(hh[j]));
  }
  uint2 ph, pl;
  ph.x = hh[0] | ((unsigned)hh[1] << 16); ph.y = hh[2] | ((unsigned)hh[3] << 16);
  pl.x = ll[0] | ((unsigned)ll[1] << 16); pl.y = ll[2] | ((unsigned)ll[3] << 16);
  *reinterpret_cast<uint2*>(&xh[i]) = ph;
  *reinterpret_cast<uint2*>(&xl[i]) = pl;
}

// ---------------------------------------------------------------------------
// W (fp32 [K=2048][N]) -> W^T hi/lo (bf16 [rowOff+N][2048])
// ---------------------------------------------------------------------------
__global__ __launch_bounds__(256)
void convert_wT_k(const float* __restrict__ W, int N, int rowOff,
                  unsigned short* __restrict__ wTh,
                  unsigned short* __restrict__ wTl) {
  __shared__ float tile[32][33];
  const int k0 = blockIdx.y * 32;
  const int n0 = blockIdx.x * 32;
  const int tid = threadIdx.x;
  {
    int r = tid >> 3, c4 = (tid & 7) * 4;
    float4 v = *reinterpret_cast<const float4*>(&W[(size_t)(k0 + r) * N + n0 + c4]);
    tile[r][c4 + 0] = v.x; tile[r][c4 + 1] = v.y;
    tile[r][c4 + 2] = v.z; tile[r][c4 + 3] = v.w;
  }
  __syncthreads();
  int n = tid >> 3, kc = (tid & 7) * 4;
  unsigned short hh[4], ll[4];
#pragma unroll
  for (int j = 0; j < 4; ++j) {
    float f = tile[kc + j][n];
    hh[j] = f2bf(f);
    ll[j] = f2bf(f - bf2f(hh[j]));
  }
  size_t o = (size_t)(rowOff + n0 + n) * HID + k0 + kc;
  uint2 ph, pl;
  ph.x = hh[0] | ((unsigned)hh[1] << 16); ph.y = hh[2] | ((unsigned)hh[3] << 16);
  pl.x = ll[0] | ((unsigned)ll[1] << 16); pl.y = ll[2] | ((unsigned)ll[3] << 16);
  *reinterpret_cast<uint2*>(&wTh[o]) = ph;
  *reinterpret_cast<uint2*>(&wTl[o]) = pl;
}

// ---------------------------------------------------------------------------
// Split-bf16 GEMM, single-generation geometry:
//   C = relu(A@W + b), A = Ah+Al, B^T = Bh+Bl (bf16 splits)
//   C = Ah@Bh + Ah@Bl + Al@Bh   (fp32 accum; lo*lo dropped ~2^-18)
// BM=256, BN=320, BK=32 -> 16x16 = 256 tiles = EXACTLY 1 block/CU, 1 gen.
// 512 thr (8 waves 2M x 4N), wave-tile 128x80 (m=8, n=5 frags):
//   13.2 LDS-B/kFLOP (was 20.3), MFMA:LDS-cycle 1.9:1 (was 1.24).
// LDS double buffer 2 x 72KB = 144 KB. Per K-tile:
//   stage(t+1 -> other buf, 9 loads) | 3 zerofill nt-stores | vmcnt(12)
//   | barrier | computeTile(cur) | barrier
// Loads get a full compute phase to land; vmcnt counted (12 = 9+3), never
// drained mid-loop. Zerofill of disp+comb (403MB) rides HBM headroom:
// 256 blk x 64 tiles x 512 thr x 48B == 2*DISP_ELEMS*4 exactly.
// Slot-XOR swizzle both sides (PMC-verified 0 conflicts, r3).
// ---------------------------------------------------------------------------
__global__ __launch_bounds__(512, 2)
void gemm_split_k(const unsigned short* __restrict__ Ahg,
                  const unsigned short* __restrict__ Alg,
                  const unsigned short* __restrict__ Bhg,
                  const unsigned short* __restrict__ Blg,
                  const float* __restrict__ bi1, const float* __restrict__ br1,
                  const float* __restrict__ bu1, float* __restrict__ h_i,
                  float* __restrict__ h_r, float* __restrict__ h_u,
                  float* __restrict__ dzero) {
  // per-buffer layout (shorts): Ah@0(8192) Al@8192 Bh@16384(10240) Bl@26624
  __shared__ unsigned short lds[73728];          // 2 x 36864 shorts = 144 KB
  const int bid  = blockIdx.x;
  const int tid  = threadIdx.x;
  const int lane = tid & 63;
  const int wave = tid >> 6;
  const int lr   = lane & 15;
  const int slot = lane >> 4;                    // k-slot 0..3

  // XCD swizzle: xcd = bid&7 gets a 2-M-stripe x 16-N (blocks sharing a B
  // panel are co-resident on the same XCD -> L2 shares the B fetch)
  const int idx = bid >> 3;                      // 0..31
  const int mt  = ((bid & 7) << 1) | (idx >> 4); // 0..15
  const int nt  = idx & 15;                      // 0..15
  const int row0  = mt * 256;
  const int bcol0 = nt * 320;

  // ---- staging map: 9 x 16B chunks per thread per K-tile (72KB total)
  // chunk c = (wave*9+j)*64 + lane; sections Ah[0,1024) Al[1024,2048)
  // Bh[2048,3328) Bl[3328,4608) -- all boundaries multiples of 64.
  const unsigned short* gsrc[9];
#pragma unroll
  for (int j = 0; j < 9; ++j) {
    int c = (wave * 9 + j) * 64 + lane;
    const unsigned short* base;
    int sidx, rowg;
    if (c < 2048) {                              // A hi/lo: 256 rows x 4 slots
      sidx = c & 1023;
      base = (c < 1024) ? Ahg : Alg;
      rowg = row0 + (sidx >> 2);
    } else {                                     // B hi/lo: 320 rows x 4 slots
      sidx = (c < 3328) ? (c - 2048) : (c - 3328);
      base = (c < 3328) ? Bhg : Blg;
      rowg = bcol0 + (sidx >> 2);
    }
    int q  = sidx & 3;
    int qs = q ^ (((sidx >> 2) >> 1) & 3);       // pre-swizzled source slot
    gsrc[j] = base + (size_t)rowg * HID + qs * 8;
  }
  const int ldsbase = wave * 4608 + lane * 8;    // linear LDS dest (shorts)

  // ---- ds_read offsets (swizzled, conflict-free)
  int aoff[8], boff[5];
#pragma unroll
  for (int m = 0; m < 8; ++m) {
    int ra = (wave >> 2) * 128 + m * 16 + lr;    // 0..255
    aoff[m] = ra * 32 + (slot ^ ((ra >> 1) & 3)) * 8;
  }
#pragma unroll
  for (int n = 0; n < 5; ++n) {
    int rb = (wave & 3) * 80 + n * 16 + lr;      // 0..319
    boff[n] = rb * 32 + (slot ^ ((rb >> 1) & 3)) * 8;
  }

  f32x4 acc[8][5];
#pragma unroll
  for (int m = 0; m < 8; ++m)
#pragma unroll
    for (int n = 0; n < 5; ++n) acc[m][n] = (f32x4){0.f, 0.f, 0.f, 0.f};

  auto stage = [&](int kt, unsigned short* buf) {
#pragma unroll
    for (int j = 0; j < 9; ++j)
      gload16(gsrc[j] + kt * 32, buf + ldsbase + j * 512);
  };
  auto computeTile = [&](const unsigned short* bb) {
    bf16x8 bvh[5], bvl[5];
#pragma unroll
    for (int n = 0; n < 5; ++n) {
      bvh[n] = ldsread(&bb[16384 + boff[n]]);
      bvl[n] = ldsread(&bb[26624 + boff[n]]);
    }
#pragma unroll
    for (int m = 0; m < 8; ++m) {
      bf16x8 ah = ldsread(&bb[aoff[m]]);
      bf16x8 al = ldsread(&bb[8192 + aoff[m]]);
      __builtin_amdgcn_s_setprio(1);
#pragma unroll
      for (int n = 0; n < 5; ++n) {
        acc[m][n] = __builtin_amdgcn_mfma_f32_16x16x32_bf16(ah, bvh[n], acc[m][n], 0, 0, 0);
        acc[m][n] = __builtin_amdgcn_mfma_f32_16x16x32_bf16(ah, bvl[n], acc[m][n], 0, 0, 0);
        acc[m][n] = __builtin_amdgcn_mfma_f32_16x16x32_bf16(al, bvh[n], acc[m][n], 0, 0, 0);
      }
      __builtin_amdgcn_s_setprio(0);
    }
  };

  unsigned short* b0 = &lds[0];
  unsigned short* b1 = &lds[36864];
  const bool dz = (dzero != nullptr);
  f32x4* d4 = (f32x4*)dzero;
  const f32x4 zv = (f32x4){0.f, 0.f, 0.f, 0.f};

  stage(0, b0);                                  // prologue: tile 0 in flight

#pragma unroll 1
  for (int t = 0; t < 64; ++t) {
    unsigned short* cur = (t & 1) ? b1 : b0;
    unsigned short* nxt = (t & 1) ? b0 : b1;
    if (t < 63) stage(t + 1, nxt);               // 9 loads, early issue
    if (dz) {                                    // 3 coalesced nt-stores
      size_t zb = ((size_t)(bid * 64 + t) * 3) * 512 + tid;
      __builtin_nontemporal_store(zv, d4 + zb);
      __builtin_nontemporal_store(zv, d4 + zb + 512);
      __builtin_nontemporal_store(zv, d4 + zb + 1024);
    }
    // wait: tile t's 9 loads landed (newest 12/9/3/0 may stay in flight)
    if (t < 63) {
      if (dz) asm volatile("s_waitcnt vmcnt(12)" ::: "memory");
      else    asm volatile("s_waitcnt vmcnt(9)"  ::: "memory");
    } else {
      if (dz) asm volatile("s_waitcnt vmcnt(3)"  ::: "memory");
      else    asm volatile("s_waitcnt vmcnt(0)"  ::: "memory");
    }
    __builtin_amdgcn_s_barrier();                // all waves' t-loads in LDS
    __builtin_amdgcn_sched_barrier(0);
    computeTile(cur);
    __builtin_amdgcn_s_barrier();                // cur free for stage(t+2)
  }

  // ---- epilogue: bias + relu + store (BN=320 panel may span h_i/h_r/h_u;
  // frag col-base is a multiple of 16 and boundaries 1024/3072 are too,
  // so the 3-way select is wave-uniform per frag)
#pragma unroll
  for (int n = 0; n < 5; ++n) {
    int cbase = nt * 320 + (wave & 3) * 80 + n * 16;
    float* C; const float* bias; int ldc, coff;
    if (cbase < 1024)      { C = h_i; bias = bi1; ldc = 1024; coff = 0; }
    else if (cbase < 3072) { C = h_r; bias = br1; ldc = 2048; coff = 1024; }
    else                   { C = h_u; bias = bu1; ldc = 2048; coff = 3072; }
    int cl = cbase - coff + lr;
    float bn = bias[cl];
#pragma unroll
    for (int m = 0; m < 8; ++m) {
      int rbase = row0 + (wave >> 2) * 128 + m * 16 + slot * 4;
#pragma unroll
      for (int j = 0; j < 4; ++j)
        C[(size_t)(rbase + j) * ldc + cl] = fmaxf(acc[m][n][j] + bn, 0.f);
    }
  }
}

// ---------------------------------------------------------------------------
// Per-token second layers + softmax + top-1 flag. One block per token.
// ---------------------------------------------------------------------------
__global__ __launch_bounds__(256)
void router_k(const float* __restrict__ h_i, const float* __restrict__ h_r,
              const float* __restrict__ h_u,
              const float* __restrict__ Wi2, const float* __restrict__ bi2,
              const float* __restrict__ Wr2, const float* __restrict__ br2,
              const float* __restrict__ Wu2, const float* __restrict__ bu2,
              float* __restrict__ router_probs, float* __restrict__ importance,
              int* __restrict__ expert_used) {
  const int t = blockIdx.x;
  const int tid = threadIdx.x;

  float acc_i;
  {
    float4 hv = *reinterpret_cast<const float4*>(&h_i[(size_t)t * 1024 + tid * 4]);
    float4 wv = *reinterpret_cast<const float4*>(&Wi2[tid * 4]);
    acc_i = hv.x * wv.x + hv.y * wv.y + hv.z * wv.z + hv.w * wv.w;
  }

  float accR[8], accU[8];
#pragma unroll
  for (int e = 0; e < 8; ++e) { accR[e] = 0.f; accU[e] = 0.f; }

  const int i0 = tid * 8;
  {
    float4 h0 = *reinterpret_cast<const float4*>(&h_r[(size_t)t * 2048 + i0]);
    float4 h1 = *reinterpret_cast<const float4*>(&h_r[(size_t)t * 2048 + i0 + 4]);
    float hr[8] = {h0.x, h0.y, h0.z, h0.w, h1.x, h1.y, h1.z, h1.w};
#pragma unroll
    for (int q = 0; q < 8; ++q) {
      float4 w0 = *reinterpret_cast<const float4*>(&Wr2[(size_t)(i0 + q) * 8]);
      float4 w1 = *reinterpret_cast<const float4*>(&Wr2[(size_t)(i0 + q) * 8 + 4]);
      accR[0] = fmaf(hr[q], w0.x, accR[0]); accR[1] = fmaf(hr[q], w0.y, accR[1]);
      accR[2] = fmaf(hr[q], w0.z, accR[2]); accR[3] = fmaf(hr[q], w0.w, accR[3]);
      accR[4] = fmaf(hr[q], w1.x, accR[4]); accR[5] = fmaf(hr[q], w1.y, accR[5]);
      accR[6] = fmaf(hr[q], w1.z, accR[6]); accR[7] = fmaf(hr[q], w1.w, accR[7]);
    }
  }
  {
    float4 h0 = *reinterpret_cast<const float4*>(&h_u[(size_t)t * 2048 + i0]);
    float4 h1 = *reinterpret_cast<const float4*>(&h_u[(size_t)t * 2048 + i0 + 4]);
    float hu[8] = {h0.x, h0.y, h0.z, h0.w, h1.x, h1.y, h1.z, h1.w};
#pragma unroll
    for (int q = 0; q < 8; ++q) {
      float4 w0 = *reinterpret_cast<const float4*>(&Wu2[(size_t)(i0 + q) * 8]);
      float4 w1 = *reinterpret_cast<const float4*>(&Wu2[(size_t)(i0 + q) * 8 + 4]);
      accU[0] = fmaf(hu[q], w0.x, accU[0]); accU[1] = fmaf(hu[q], w0.y, accU[1]);
      accU[2] = fmaf(hu[q], w0.z, accU[2]); accU[3] = fmaf(hu[q], w0.w, accU[3]);
      accU[4] = fmaf(hu[q], w1.x, accU[4]); accU[5] = fmaf(hu[q], w1.y, accU[5]);
      accU[6] = fmaf(hu[q], w1.z, accU[6]); accU[7] = fmaf(hu[q], w1.w, accU[7]);
    }
  }

  float vals[17];
  vals[0] = acc_i;
#pragma unroll
  for (int e = 0; e < 8; ++e) { vals[1 + e] = accR[e]; vals[9 + e] = accU[e]; }
#pragma unroll
  for (int k = 0; k < 17; ++k) {
    float v = vals[k];
    v += __shfl_xor(v, 1);  v += __shfl_xor(v, 2);  v += __shfl_xor(v, 4);
    v += __shfl_xor(v, 8);  v += __shfl_xor(v, 16); v += __shfl_xor(v, 32);
    vals[k] = v;
  }
  __shared__ float red[4][17];
  const int lane = tid & 63, wid = tid >> 6;
  if (lane == 0) {
#pragma unroll
    for (int k = 0; k < 17; ++k) red[wid][k] = vals[k];
  }
  __syncthreads();
  if (tid == 0) {
    float s[17];
#pragma unroll
    for (int k = 0; k < 17; ++k)
      s[k] = red[0][k] + red[1][k] + red[2][k] + red[3][k];
    float imp = 1.f / (1.f + expf(-(s[0] + bi2[0])));
    importance[t] = imp;
    bool useImp = imp > 0.5f;
    float logits[8];
#pragma unroll
    for (int e = 0; e < 8; ++e)
      logits[e] = useImp ? (s[1 + e] + br2[e]) : (s[9 + e] + bu2[e]);
    float mx = logits[0];
#pragma unroll
    for (int e = 1; e < 8; ++e) mx = fmaxf(mx, logits[e]);
    float ex[8], sum = 0.f;
#pragma unroll
    for (int e = 0; e < 8; ++e) { ex[e] = expf(logits[e] - mx); sum += ex[e]; }
    float p[8];
#pragma unroll
    for (int e = 0; e < 8; ++e) p[e] = ex[e] / sum;
#pragma unroll
    for (int e = 0; e < 8; ++e) router_probs[(size_t)t * 8 + e] = p[e];
    int e1 = 0; float p1 = p[0];
#pragma unroll
    for (int e = 1; e < 8; ++e) if (p[e] > p1) { p1 = p[e]; e1 = e; }
    expert_used[e1] = 1;   // benign race: all writers store 1
  }
}

// ---------------------------------------------------------------------------
// Scatter + aux partial reduction. 16 blocks x 256 thr (one thread per token).
// ---------------------------------------------------------------------------
__global__ __launch_bounds__(256)
void scatter_aux_k(const float* __restrict__ router_probs,
                   const int* __restrict__ expert_used,
                   const float* __restrict__ importance,
                   float* __restrict__ disp, float* __restrict__ comb,
                   float* __restrict__ partials) {
  const int tid = threadIdx.x;
  const int t = blockIdx.x * 256 + tid;
  float4 a = *reinterpret_cast<const float4*>(&router_probs[(size_t)t * 8]);
  float4 b = *reinterpret_cast<const float4*>(&router_probs[(size_t)t * 8 + 4]);
  float p[8] = {a.x, a.y, a.z, a.w, b.x, b.y, b.z, b.w};
  int e1 = 0; float p1 = p[0];
#pragma unroll
  for (int e = 1; e < 8; ++e) if (p[e] > p1) { p1 = p[e]; e1 = e; }
  int e2 = 0; float p2 = -1.f;
#pragma unroll
  for (int e = 0; e < 8; ++e) {
    if (e == e1) continue;
    if (p[e] > p2) { p2 = p[e]; e2 = e; }
  }
  float s = p1 + p2;
  size_t base = (size_t)t * NEXP * CAP;
  disp[base + (size_t)e1 * CAP + 0] = 1.f;
  comb[base + (size_t)e1 * CAP + 0] = p1 / s;
  int pos = expert_used[e2];
  disp[base + (size_t)e2 * CAP + pos] = 1.f;
  comb[base + (size_t)e2 * CAP + pos] = p2 / s;

  // ---- aux partials
  float mk = importance[t] > 0.5f ? 1.f : 0.f;
  float vals[16];
#pragma unroll
  for (int e = 0; e < 8; ++e) { vals[e] = p[e]; vals[8 + e] = p[e] * mk; }
#pragma unroll
  for (int k = 0; k < 16; ++k) {
    float v = vals[k];
    v += __shfl_xor(v, 1);  v += __shfl_xor(v, 2);  v += __shfl_xor(v, 4);
    v += __shfl_xor(v, 8);  v += __shfl_xor(v, 16); v += __shfl_xor(v, 32);
    vals[k] = v;
  }
  __shared__ float red[4][16];
  const int lane = tid & 63, wid = tid >> 6;
  if (lane == 0) {
#pragma unroll
    for (int k = 0; k < 16; ++k) red[wid][k] = vals[k];
  }
  __syncthreads();
  if (tid < 16)
    atomicAdd(&partials[tid],
              red[0][tid] + red[1][tid] + red[2][tid] + red[3][tid]);
}

// ---------------------------------------------------------------------------
// Aux finalize from partials; zero partials + flag tail (comb must end 0).
// ---------------------------------------------------------------------------
__global__ __launch_bounds__(64)
void aux_final_k(float* __restrict__ partials, float* __restrict__ aux_out,
                 float* __restrict__ flag_tail) {
  const int tid = threadIdx.x;
  float s[16];
#pragma unroll
  for (int k = 0; k < 16; ++k) s[k] = partials[k];
  if (tid == 0) {
    float entropy_loss = 0.f;
#pragma unroll
    for (int e = 0; e < 8; ++e) {
      float rppe = s[e] / (float)M_TOK;
      entropy_loss += rppe * logf(rppe * 8.f + 1e-9f);
    }
    float tot = 0.f;
#pragma unroll
    for (int e = 0; e < 8; ++e) tot += s[8 + e] + 1e-9f;
    float imp_entropy = 0.f;
#pragma unroll
    for (int e = 0; e < 8; ++e) {
      float ipe = (s[8 + e] + 1e-9f) / tot;
      imp_entropy -= ipe * logf(ipe + 1e-9f);
    }
    aux_out[0] = entropy_loss - 0.1f * (imp_entropy / logf(8.f));
  }
  if (tid < 16) partials[tid] = 0.f;
  if (tid >= 16 && tid < 32) flag_tail[tid - 16] = 0.f;
}

// ---------------------------------------------------------------------------
extern "C" void kernel_launch(void* const* d_in, const int* in_sizes, int n_in,
                              void* d_out, int out_size, void* d_ws,
                              size_t ws_size, hipStream_t stream) {
  const float* x   = (const float*)d_in[0];
  const float* Wi1 = (const float*)d_in[1];
  const float* bi1 = (const float*)d_in[2];
  const float* Wi2 = (const float*)d_in[3];
  const float* bi2 = (const float*)d_in[4];
  const float* Wr1 = (const float*)d_in[5];
  const float* br1 = (const float*)d_in[6];
  const float* Wr2 = (const float*)d_in[7];
  const float* br2 = (const float*)d_in[8];
  const float* Wu1 = (const float*)d_in[9];
  const float* bu1 = (const float*)d_in[10];
  const float* Wu2 = (const float*)d_in[11];
  const float* bu2 = (const float*)d_in[12];

  float* out  = (float*)d_out;
  float* disp = out;
  float* comb = out + DISP_ELEMS;
  float* rp   = out + 2 * DISP_ELEMS;            // 32768
  float* aux  = out + 2 * DISP_ELEMS + 32768;    // 1
  float* imp  = aux + 1;                         // 4096

  // scratch layout (bytes):
  //   xh 16.78M | xl 16.78M | wTh 20.97M | wTl 20.97M | h_i 16.78M | h_r 33.55M | h_u 33.55M
  const size_t xh_b  = (size_t)M_TOK * HID * 2;
  const size_t wT_b  = (size_t)NTOT * HID * 2;
  const size_t hi_b  = (size_t)M_TOK * 1024 * 4;
  const size_t hr_b  = (size_t)M_TOK * 2048 * 4;
  const size_t need  = 2 * xh_b + 2 * wT_b + hi_b + 2 * hr_b + 256;
  const bool ws_ok = (ws_size >= need);
  char* scratch = ws_ok ? (char*)d_ws : (char*)comb;  // comb region 201MB > 153MB

  unsigned short* xh  = (unsigned short*)scratch;
  unsigned short* xl  = (unsigned short*)(scratch + xh_b);
  unsigned short* wTh = (unsigned short*)(scratch + 2 * xh_b);
  unsigned short* wTl = (unsigned short*)(scratch + 2 * xh_b + wT_b);
  float* h_i = (float*)(scratch + 2 * xh_b + 2 * wT_b);
  float* h_r = h_i + (size_t)M_TOK * 1024;
  float* h_u = h_r + (size_t)M_TOK * 2048;
  // comb tail (never scatter-written: max scatter index < DISP_ELEMS-1534):
  //   partials @ -48 (16 floats), flags @ -16 (16 ints)
  int*   flags    = (int*)(comb + DISP_ELEMS - 16);
  float* partials = comb + DISP_ELEMS - 48;

  // 1. zeroing: if ws_ok, the in-loop nt-stores inside gemm cover disp+comb
  //    (incl. partials+flags). Otherwise fall back to memsets.
  if (!ws_ok) {
    (void)hipMemsetAsync(disp, 0, DISP_ELEMS * sizeof(float), stream);
    (void)hipMemsetAsync(flags, 0, 16 * sizeof(float), stream);
  }

  // 2. convert inputs to bf16 hi/lo (W transposed into concat [5120][2048])
  convert_x_k<<<(M_TOK * HID / 4) / 256, 256, 0, stream>>>(x, xh, xl);
  convert_wT_k<<<dim3(1024 / 32, HID / 32), 256, 0, stream>>>(Wi1, 1024, 0, wTh, wTl);
  convert_wT_k<<<dim3(2048 / 32, HID / 32), 256, 0, stream>>>(Wr1, 2048, 1024, wTh, wTl);
  convert_wT_k<<<dim3(2048 / 32, HID / 32), 256, 0, stream>>>(Wu1, 2048, 3072, wTh, wTl);

  // 3. fused split-bf16 MFMA GEMM: 256 blocks = 1/CU, single generation
  gemm_split_k<<<256, 512, 0, stream>>>(xh, xl, wTh, wTl, bi1, br1, bu1,
                                        h_i, h_r, h_u,
                                        ws_ok ? disp : (float*)nullptr);

  // 4. router probs / importance / top-1 flags
  router_k<<<M_TOK, 256, 0, stream>>>(h_i, h_r, h_u, Wi2, bi2, Wr2, br2,
                                      Wu2, bu2, rp, imp, flags);

  // 5. zero comb if it was used as scratch (covers partials; keep flag tail)
  if (!ws_ok)
    (void)hipMemsetAsync(comb, 0, (DISP_ELEMS - 16) * sizeof(float), stream);

  // 6. scatter + aux partial reduction
  scatter_aux_k<<<M_TOK / 256, 256, 0, stream>>>(rp, flags, imp, disp, comb,
                                                 partials);

  // 7. aux finalize + zero partials/flag tail
  aux_final_k<<<1, 64, 0, stream>>>(partials, aux, (float*)flags);
}

// Round 10
// 292.754 us; speedup vs baseline: 1.5790x; 1.1691x over previous
//
#include <hip/hip_runtime.h>
#include <math.h>

#define M_TOK 4096           // B*S
#define HID   2048
#define NEXP  8
#define CAP   1536
#define DISP_ELEMS 50331648ull   // 4096*8*1536
#define NTOT  5120               // 1024 + 2048 + 2048 (concat N)
#define ZTOT4 25165824ull        // (2*DISP_ELEMS)/4 float4s

typedef __attribute__((ext_vector_type(8))) short bf16x8;
typedef __attribute__((ext_vector_type(4))) float f32x4;

__device__ __forceinline__ unsigned short f2bf(float f) {
  unsigned u = __float_as_uint(f);
  unsigned r = u + 0x7FFFu + ((u >> 16) & 1u);   // RNE (finite inputs)
  return (unsigned short)(r >> 16);
}
__device__ __forceinline__ float bf2f(unsigned short h) {
  return __uint_as_float(((unsigned)h) << 16);
}

__device__ __forceinline__ void gload16(const void* g, void* l) {
  __builtin_amdgcn_global_load_lds(
      (const __attribute__((address_space(1))) void*)g,
      (__attribute__((address_space(3))) void*)l, 16, 0, 0);
}
__device__ __forceinline__ bf16x8 ldsread(const unsigned short* p) {
  return *reinterpret_cast<const bf16x8*>(p);
}

// ---------------------------------------------------------------------------
// x (fp32 [M][K]) -> x_hi, x_lo (bf16 [M][K])
// ---------------------------------------------------------------------------
__global__ __launch_bounds__(256)
void convert_x_k(const float* __restrict__ x, unsigned short* __restrict__ xh,
                 unsigned short* __restrict__ xl) {
  size_t i = ((size_t)blockIdx.x * 256 + threadIdx.x) * 4;
  float4 v = *reinterpret_cast<const float4*>(&x[i]);
  float f[4] = {v.x, v.y, v.z, v.w};
  unsigned short hh[4], ll[4];
#pragma unroll
  for (int j = 0; j < 4; ++j) {
    hh[j] = f2bf(f[j]);
    ll[j] = f2bf(f[j] - bf2f(hh[j]));
  }
  uint2 ph, pl;
  ph.x = hh[0] | ((unsigned)hh[1] << 16); ph.y = hh[2] | ((unsigned)hh[3] << 16);
  pl.x = ll[0] | ((unsigned)ll[1] << 16); pl.y = ll[2] | ((unsigned)ll[3] << 16);
  *reinterpret_cast<uint2*>(&xh[i]) = ph;
  *reinterpret_cast<uint2*>(&xl[i]) = pl;
}

// ---------------------------------------------------------------------------
// All three W (fp32 [K=2048][N]) -> W^T hi/lo (bf16 [5120][2048]), one launch.
// grid.x: 0..31 -> Wi1 (N=1024), 32..95 -> Wr1, 96..159 -> Wu1. grid.y = k0/32.
// ---------------------------------------------------------------------------
__global__ __launch_bounds__(256)
void convert_wT_k(const float* __restrict__ Wi1, const float* __restrict__ Wr1,
                  const float* __restrict__ Wu1,
                  unsigned short* __restrict__ wTh,
                  unsigned short* __restrict__ wTl) {
  __shared__ float tile[32][33];
  const int bx = blockIdx.x;
  const float* W; int N, rowOff, nb;
  if (bx < 32)      { W = Wi1; N = 1024; rowOff = 0;    nb = bx; }
  else if (bx < 96) { W = Wr1; N = 2048; rowOff = 1024; nb = bx - 32; }
  else              { W = Wu1; N = 2048; rowOff = 3072; nb = bx - 96; }
  const int k0 = blockIdx.y * 32;
  const int n0 = nb * 32;
  const int tid = threadIdx.x;
  {
    int r = tid >> 3, c4 = (tid & 7) * 4;
    float4 v = *reinterpret_cast<const float4*>(&W[(size_t)(k0 + r) * N + n0 + c4]);
    tile[r][c4 + 0] = v.x; tile[r][c4 + 1] = v.y;
    tile[r][c4 + 2] = v.z; tile[r][c4 + 3] = v.w;
  }
  __syncthreads();
  int n = tid >> 3, kc = (tid & 7) * 4;
  unsigned short hh[4], ll[4];
#pragma unroll
  for (int j = 0; j < 4; ++j) {
    float f = tile[kc + j][n];
    hh[j] = f2bf(f);
    ll[j] = f2bf(f - bf2f(hh[j]));
  }
  size_t o = (size_t)(rowOff + n0 + n) * HID + k0 + kc;
  uint2 ph, pl;
  ph.x = hh[0] | ((unsigned)hh[1] << 16); ph.y = hh[2] | ((unsigned)hh[3] << 16);
  pl.x = ll[0] | ((unsigned)ll[1] << 16); pl.y = ll[2] | ((unsigned)ll[3] << 16);
  *reinterpret_cast<uint2*>(&wTh[o]) = ph;
  *reinterpret_cast<uint2*>(&wTl[o]) = pl;
}

// ---------------------------------------------------------------------------
// Split-bf16 GEMM, single-generation geometry (r9-proven, unchanged):
// BM=256, BN=320, BK=32 -> 256 blocks = 1/CU. Wave-tile 128x80.
// LDS dbuf 2x72KB. Counted vmcnt; in-loop nt-store zerofill of disp+comb.
// ---------------------------------------------------------------------------
__global__ __launch_bounds__(512, 2)
void gemm_split_k(const unsigned short* __restrict__ Ahg,
                  const unsigned short* __restrict__ Alg,
                  const unsigned short* __restrict__ Bhg,
                  const unsigned short* __restrict__ Blg,
                  const float* __restrict__ bi1, const float* __restrict__ br1,
                  const float* __restrict__ bu1, float* __restrict__ h_i,
                  float* __restrict__ h_r, float* __restrict__ h_u,
                  float* __restrict__ dzero) {
  __shared__ unsigned short lds[73728];          // 2 x 36864 shorts = 144 KB
  const int bid  = blockIdx.x;
  const int tid  = threadIdx.x;
  const int lane = tid & 63;
  const int wave = tid >> 6;
  const int lr   = lane & 15;
  const int slot = lane >> 4;

  const int idx = bid >> 3;
  const int mt  = ((bid & 7) << 1) | (idx >> 4);
  const int nt  = idx & 15;
  const int row0  = mt * 256;
  const int bcol0 = nt * 320;

  const unsigned short* gsrc[9];
#pragma unroll
  for (int j = 0; j < 9; ++j) {
    int c = (wave * 9 + j) * 64 + lane;
    const unsigned short* base;
    int sidx, rowg;
    if (c < 2048) {
      sidx = c & 1023;
      base = (c < 1024) ? Ahg : Alg;
      rowg = row0 + (sidx >> 2);
    } else {
      sidx = (c < 3328) ? (c - 2048) : (c - 3328);
      base = (c < 3328) ? Bhg : Blg;
      rowg = bcol0 + (sidx >> 2);
    }
    int q  = sidx & 3;
    int qs = q ^ (((sidx >> 2) >> 1) & 3);
    gsrc[j] = base + (size_t)rowg * HID + qs * 8;
  }
  const int ldsbase = wave * 4608 + lane * 8;

  int aoff[8], boff[5];
#pragma unroll
  for (int m = 0; m < 8; ++m) {
    int ra = (wave >> 2) * 128 + m * 16 + lr;
    aoff[m] = ra * 32 + (slot ^ ((ra >> 1) & 3)) * 8;
  }
#pragma unroll
  for (int n = 0; n < 5; ++n) {
    int rb = (wave & 3) * 80 + n * 16 + lr;
    boff[n] = rb * 32 + (slot ^ ((rb >> 1) & 3)) * 8;
  }

  f32x4 acc[8][5];
#pragma unroll
  for (int m = 0; m < 8; ++m)
#pragma unroll
    for (int n = 0; n < 5; ++n) acc[m][n] = (f32x4){0.f, 0.f, 0.f, 0.f};

  auto stage = [&](int kt, unsigned short* buf) {
#pragma unroll
    for (int j = 0; j < 9; ++j)
      gload16(gsrc[j] + kt * 32, buf + ldsbase + j * 512);
  };
  auto computeTile = [&](const unsigned short* bb) {
    bf16x8 bvh[5], bvl[5];
#pragma unroll
    for (int n = 0; n < 5; ++n) {
      bvh[n] = ldsread(&bb[16384 + boff[n]]);
      bvl[n] = ldsread(&bb[26624 + boff[n]]);
    }
#pragma unroll
    for (int m = 0; m < 8; ++m) {
      bf16x8 ah = ldsread(&bb[aoff[m]]);
      bf16x8 al = ldsread(&bb[8192 + aoff[m]]);
      __builtin_amdgcn_s_setprio(1);
#pragma unroll
      for (int n = 0; n < 5; ++n) {
        acc[m][n] = __builtin_amdgcn_mfma_f32_16x16x32_bf16(ah, bvh[n], acc[m][n], 0, 0, 0);
        acc[m][n] = __builtin_amdgcn_mfma_f32_16x16x32_bf16(ah, bvl[n], acc[m][n], 0, 0, 0);
        acc[m][n] = __builtin_amdgcn_mfma_f32_16x16x32_bf16(al, bvh[n], acc[m][n], 0, 0, 0);
      }
      __builtin_amdgcn_s_setprio(0);
    }
  };

  unsigned short* b0 = &lds[0];
  unsigned short* b1 = &lds[36864];
  const bool dz = (dzero != nullptr);
  f32x4* d4 = (f32x4*)dzero;
  const f32x4 zv = (f32x4){0.f, 0.f, 0.f, 0.f};

  stage(0, b0);

#pragma unroll 1
  for (int t = 0; t < 64; ++t) {
    unsigned short* cur = (t & 1) ? b1 : b0;
    unsigned short* nxt = (t & 1) ? b0 : b1;
    if (t < 63) stage(t + 1, nxt);
    if (dz) {
      size_t zb = ((size_t)(bid * 64 + t) * 3) * 512 + tid;
      __builtin_nontemporal_store(zv, d4 + zb);
      __builtin_nontemporal_store(zv, d4 + zb + 512);
      __builtin_nontemporal_store(zv, d4 + zb + 1024);
    }
    if (t < 63) {
      if (dz) asm volatile("s_waitcnt vmcnt(12)" ::: "memory");
      else    asm volatile("s_waitcnt vmcnt(9)"  ::: "memory");
    } else {
      if (dz) asm volatile("s_waitcnt vmcnt(3)"  ::: "memory");
      else    asm volatile("s_waitcnt vmcnt(0)"  ::: "memory");
    }
    __builtin_amdgcn_s_barrier();
    __builtin_amdgcn_sched_barrier(0);
    computeTile(cur);
    __builtin_amdgcn_s_barrier();
  }

#pragma unroll
  for (int n = 0; n < 5; ++n) {
    int cbase = nt * 320 + (wave & 3) * 80 + n * 16;
    float* C; const float* bias; int ldc, coff;
    if (cbase < 1024)      { C = h_i; bias = bi1; ldc = 1024; coff = 0; }
    else if (cbase < 3072) { C = h_r; bias = br1; ldc = 2048; coff = 1024; }
    else                   { C = h_u; bias = bu1; ldc = 2048; coff = 3072; }
    int cl = cbase - coff + lr;
    float bn = bias[cl];
#pragma unroll
    for (int m = 0; m < 8; ++m) {
      int rbase = row0 + (wave >> 2) * 128 + m * 16 + slot * 4;
#pragma unroll
      for (int j = 0; j < 4; ++j)
        C[(size_t)(rbase + j) * ldc + cl] = fmaxf(acc[m][n][j] + bn, 0.f);
    }
  }
}

// ---------------------------------------------------------------------------
// Router v2: 256 blocks x 16 tokens. W2 staged ONCE per block into LDS
// (row stride padded to 9 floats -> lane l hits bank 9l mod 32: conflict-free
// for the stride-64 lane->k map). One wave per token; per-wave butterfly
// reduce; no syncthreads inside the token loop.
// ---------------------------------------------------------------------------
__global__ __launch_bounds__(256)
void router_k(const float* __restrict__ h_i, const float* __restrict__ h_r,
              const float* __restrict__ h_u,
              const float* __restrict__ Wi2, const float* __restrict__ bi2,
              const float* __restrict__ Wr2, const float* __restrict__ br2,
              const float* __restrict__ Wu2, const float* __restrict__ bu2,
              float* __restrict__ router_probs, float* __restrict__ importance,
              int* __restrict__ expert_used) {
  __shared__ float wr[18432];   // 2048 rows x 9 (8 used + pad)
  __shared__ float wu[18432];
  __shared__ float wi[1024];
  const int tid = threadIdx.x;

  for (int idx = tid; idx < 16384; idx += 256)
    wr[(idx >> 3) * 9 + (idx & 7)] = Wr2[idx];
  for (int idx = tid; idx < 16384; idx += 256)
    wu[(idx >> 3) * 9 + (idx & 7)] = Wu2[idx];
  for (int idx = tid; idx < 1024; idx += 256) wi[idx] = Wi2[idx];
  __syncthreads();

  const int w = tid >> 6, l = tid & 63;
  const float bi2v = bi2[0];

#pragma unroll 1
  for (int tt = 0; tt < 4; ++tt) {
    const int t = blockIdx.x * 16 + tt * 4 + w;
    float acc[17];
#pragma unroll
    for (int k = 0; k < 17; ++k) acc[k] = 0.f;

    const float* hi = &h_i[(size_t)t * 1024];
    const float* hr = &h_r[(size_t)t * 2048];
    const float* hu = &h_u[(size_t)t * 2048];
#pragma unroll 4
    for (int j = 0; j < 16; ++j) {
      int k = j * 64 + l;
      acc[0] = fmaf(hi[k], wi[k], acc[0]);
    }
#pragma unroll 4
    for (int j = 0; j < 32; ++j) {
      int k = j * 64 + l;
      float hrv = hr[k], huv = hu[k];
      const float* wrr = &wr[k * 9];
      const float* wuu = &wu[k * 9];
#pragma unroll
      for (int e = 0; e < 8; ++e) {
        acc[1 + e] = fmaf(hrv, wrr[e], acc[1 + e]);
        acc[9 + e] = fmaf(huv, wuu[e], acc[9 + e]);
      }
    }
#pragma unroll
    for (int k = 0; k < 17; ++k) {
      float v = acc[k];
      v += __shfl_xor(v, 1);  v += __shfl_xor(v, 2);  v += __shfl_xor(v, 4);
      v += __shfl_xor(v, 8);  v += __shfl_xor(v, 16); v += __shfl_xor(v, 32);
      acc[k] = v;
    }
    if (l == 0) {
      float imp = 1.f / (1.f + expf(-(acc[0] + bi2v)));
      importance[t] = imp;
      bool useImp = imp > 0.5f;
      float logits[8];
#pragma unroll
      for (int e = 0; e < 8; ++e)
        logits[e] = useImp ? (acc[1 + e] + br2[e]) : (acc[9 + e] + bu2[e]);
      float mx = logits[0];
#pragma unroll
      for (int e = 1; e < 8; ++e) mx = fmaxf(mx, logits[e]);
      float ex[8], sum = 0.f;
#pragma unroll
      for (int e = 0; e < 8; ++e) { ex[e] = expf(logits[e] - mx); sum += ex[e]; }
      float p[8];
#pragma unroll
      for (int e = 0; e < 8; ++e) p[e] = ex[e] / sum;
#pragma unroll
      for (int e = 0; e < 8; ++e) router_probs[(size_t)t * 8 + e] = p[e];
      int e1 = 0; float p1 = p[0];
#pragma unroll
      for (int e = 1; e < 8; ++e) if (p[e] > p1) { p1 = p[e]; e1 = e; }
      expert_used[e1] = 1;   // benign race: all writers store 1
    }
  }
}

// ---------------------------------------------------------------------------
// Scatter + aux partial reduction. 16 blocks x 256 thr.
// ---------------------------------------------------------------------------
__global__ __launch_bounds__(256)
void scatter_aux_k(const float* __restrict__ router_probs,
                   const int* __restrict__ expert_used,
                   const float* __restrict__ importance,
                   float* __restrict__ disp, float* __restrict__ comb,
                   float* __restrict__ partials) {
  const int tid = threadIdx.x;
  const int t = blockIdx.x * 256 + tid;
  float4 a = *reinterpret_cast<const float4*>(&router_probs[(size_t)t * 8]);
  float4 b = *reinterpret_cast<const float4*>(&router_probs[(size_t)t * 8 + 4]);
  float p[8] = {a.x, a.y, a.z, a.w, b.x, b.y, b.z, b.w};
  int e1 = 0; float p1 = p[0];
#pragma unroll
  for (int e = 1; e < 8; ++e) if (p[e] > p1) { p1 = p[e]; e1 = e; }
  int e2 = 0; float p2 = -1.f;
#pragma unroll
  for (int e = 0; e < 8; ++e) {
    if (e == e1) continue;
    if (p[e] > p2) { p2 = p[e]; e2 = e; }
  }
  float s = p1 + p2;
  size_t base = (size_t)t * NEXP * CAP;
  disp[base + (size_t)e1 * CAP + 0] = 1.f;
  comb[base + (size_t)e1 * CAP + 0] = p1 / s;
  int pos = expert_used[e2];
  disp[base + (size_t)e2 * CAP + pos] = 1.f;
  comb[base + (size_t)e2 * CAP + pos] = p2 / s;

  float mk = importance[t] > 0.5f ? 1.f : 0.f;
  float vals[16];
#pragma unroll
  for (int e = 0; e < 8; ++e) { vals[e] = p[e]; vals[8 + e] = p[e] * mk; }
#pragma unroll
  for (int k = 0; k < 16; ++k) {
    float v = vals[k];
    v += __shfl_xor(v, 1);  v += __shfl_xor(v, 2);  v += __shfl_xor(v, 4);
    v += __shfl_xor(v, 8);  v += __shfl_xor(v, 16); v += __shfl_xor(v, 32);
    vals[k] = v;
  }
  __shared__ float red[4][16];
  const int lane = tid & 63, wid = tid >> 6;
  if (lane == 0) {
#pragma unroll
    for (int k = 0; k < 16; ++k) red[wid][k] = vals[k];
  }
  __syncthreads();
  if (tid < 16)
    atomicAdd(&partials[tid],
              red[0][tid] + red[1][tid] + red[2][tid] + red[3][tid]);
}

// ---------------------------------------------------------------------------
__global__ __launch_bounds__(64)
void aux_final_k(float* __restrict__ partials, float* __restrict__ aux_out,
                 float* __restrict__ flag_tail) {
  const int tid = threadIdx.x;
  float s[16];
#pragma unroll
  for (int k = 0; k < 16; ++k) s[k] = partials[k];
  if (tid == 0) {
    float entropy_loss = 0.f;
#pragma unroll
    for (int e = 0; e < 8; ++e) {
      float rppe = s[e] / (float)M_TOK;
      entropy_loss += rppe * logf(rppe * 8.f + 1e-9f);
    }
    float tot = 0.f;
#pragma unroll
    for (int e = 0; e < 8; ++e) tot += s[8 + e] + 1e-9f;
    float imp_entropy = 0.f;
#pragma unroll
    for (int e = 0; e < 8; ++e) {
      float ipe = (s[8 + e] + 1e-9f) / tot;
      imp_entropy -= ipe * logf(ipe + 1e-9f);
    }
    aux_out[0] = entropy_loss - 0.1f * (imp_entropy / logf(8.f));
  }
  if (tid < 16) partials[tid] = 0.f;
  if (tid >= 16 && tid < 32) flag_tail[tid - 16] = 0.f;
}

// ---------------------------------------------------------------------------
extern "C" void kernel_launch(void* const* d_in, const int* in_sizes, int n_in,
                              void* d_out, int out_size, void* d_ws,
                              size_t ws_size, hipStream_t stream) {
  const float* x   = (const float*)d_in[0];
  const float* Wi1 = (const float*)d_in[1];
  const float* bi1 = (const float*)d_in[2];
  const float* Wi2 = (const float*)d_in[3];
  const float* bi2 = (const float*)d_in[4];
  const float* Wr1 = (const float*)d_in[5];
  const float* br1 = (const float*)d_in[6];
  const float* Wr2 = (const float*)d_in[7];
  const float* br2 = (const float*)d_in[8];
  const float* Wu1 = (const float*)d_in[9];
  const float* bu1 = (const float*)d_in[10];
  const float* Wu2 = (const float*)d_in[11];
  const float* bu2 = (const float*)d_in[12];

  float* out  = (float*)d_out;
  float* disp = out;
  float* comb = out + DISP_ELEMS;
  float* rp   = out + 2 * DISP_ELEMS;            // 32768
  float* aux  = out + 2 * DISP_ELEMS + 32768;    // 1
  float* imp  = aux + 1;                         // 4096

  const size_t xh_b  = (size_t)M_TOK * HID * 2;
  const size_t wT_b  = (size_t)NTOT * HID * 2;
  const size_t hi_b  = (size_t)M_TOK * 1024 * 4;
  const size_t hr_b  = (size_t)M_TOK * 2048 * 4;
  const size_t need  = 2 * xh_b + 2 * wT_b + hi_b + 2 * hr_b + 256;
  const bool ws_ok = (ws_size >= need);
  char* scratch = ws_ok ? (char*)d_ws : (char*)comb;

  unsigned short* xh  = (unsigned short*)scratch;
  unsigned short* xl  = (unsigned short*)(scratch + xh_b);
  unsigned short* wTh = (unsigned short*)(scratch + 2 * xh_b);
  unsigned short* wTl = (unsigned short*)(scratch + 2 * xh_b + wT_b);
  float* h_i = (float*)(scratch + 2 * xh_b + 2 * wT_b);
  float* h_r = h_i + (size_t)M_TOK * 1024;
  float* h_u = h_r + (size_t)M_TOK * 2048;
  int*   flags    = (int*)(comb + DISP_ELEMS - 16);
  float* partials = comb + DISP_ELEMS - 48;

  if (!ws_ok) {
    (void)hipMemsetAsync(disp, 0, DISP_ELEMS * sizeof(float), stream);
    (void)hipMemsetAsync(flags, 0, 16 * sizeof(float), stream);
  }

  // converts: x split + all three W^T splits (one launch)
  convert_x_k<<<(M_TOK * HID / 4) / 256, 256, 0, stream>>>(x, xh, xl);
  convert_wT_k<<<dim3(160, HID / 32), 256, 0, stream>>>(Wi1, Wr1, Wu1, wTh, wTl);

  // fused split-bf16 MFMA GEMM: 256 blocks = 1/CU, in-loop zerofill
  gemm_split_k<<<256, 512, 0, stream>>>(xh, xl, wTh, wTl, bi1, br1, bu1,
                                        h_i, h_r, h_u,
                                        ws_ok ? disp : (float*)nullptr);

  // router v2: 256 blocks x 16 tokens, W2 LDS-cached
  router_k<<<256, 256, 0, stream>>>(h_i, h_r, h_u, Wi2, bi2, Wr2, br2,
                                    Wu2, bu2, rp, imp, flags);

  if (!ws_ok)
    (void)hipMemsetAsync(comb, 0, (DISP_ELEMS - 16) * sizeof(float), stream);

  // scatter + aux partials
  scatter_aux_k<<<M_TOK / 256, 256, 0, stream>>>(rp, flags, imp, disp, comb,
                                                 partials);

  // aux finalize + zero partials/flag tail
  aux_final_k<<<1, 64, 0, stream>>>(partials, aux, (float*)flags);
}